// Round 1
// baseline (217.594 us; speedup 1.0000x reference)
//
#include <hip/hip_runtime.h>
#include <stdint.h>

// ---------- types / helpers ----------
typedef __attribute__((ext_vector_type(8))) short   short8;   // 8 bf16 (4 VGPRs)
typedef __attribute__((ext_vector_type(8))) __bf16  bf16x8;
typedef __attribute__((ext_vector_type(4))) float   floatx4;

__device__ __forceinline__ float bf2f(uint16_t h) {
    union { uint32_t u; float f; } v; v.u = ((uint32_t)h) << 16; return v.f;
}
__device__ __forceinline__ uint16_t f2bf(float f) {
    union { float f; uint32_t u; } v; v.f = f;
    uint32_t u = v.u;
    u += 0x7FFFu + ((u >> 16) & 1u);   // RNE
    return (uint16_t)(u >> 16);
}
__device__ __forceinline__ floatx4 mfma16(short8 a, short8 b, floatx4 c) {
    return __builtin_amdgcn_mfma_f32_16x16x32_bf16(
        __builtin_bit_cast(bf16x8, a), __builtin_bit_cast(bf16x8, b), c, 0, 0, 0);
}
// async global->LDS, 16B per lane
__device__ __forceinline__ void gll16(const short* g, short* l) {
    __builtin_amdgcn_global_load_lds(
        (const __attribute__((address_space(1))) uint32_t*)g,
        (__attribute__((address_space(3))) uint32_t*)l, 16, 0, 0);
}
// XOR bank swizzle: physical 16B-group = logical group ^ (row & 7).
// Applied to the GLOBAL source column during staging and to the group index
// on LDS reads. Kills the 128B-row-stride 16-way conflict. [R12: 1.94e7->5e5]

// ---------- merged f32->bf16 conversion (x, 4 weights, 4 biases, er^T) ----------
__global__ void conv_all(
    const float* __restrict__ x,
    const float* __restrict__ Wq, const float* __restrict__ Wk,
    const float* __restrict__ Wv, const float* __restrict__ Wo,
    const float* __restrict__ bq, const float* __restrict__ bk,
    const float* __restrict__ bv, const float* __restrict__ bo,
    const float* __restrict__ er,
    short* __restrict__ xb, short* __restrict__ Wb,
    short* __restrict__ ball, short* __restrict__ ErT)
{
    int blk = blockIdx.x, tid = threadIdx.x;
    if (blk < 4096) {                            // x: 1M float4
        int i = blk * 256 + tid;
        float4 v = ((const float4*)x)[i];
        ((short4*)xb)[i] = make_short4((short)f2bf(v.x), (short)f2bf(v.y),
                                       (short)f2bf(v.z), (short)f2bf(v.w));
    } else if (blk < 8192) {                     // weights: 4 x 256K float4
        int rel = blk - 4096;
        int wsel = rel >> 10;
        int i = (rel & 1023) * 256 + tid;
        const float* W = (wsel == 0) ? Wq : (wsel == 1) ? Wk : (wsel == 2) ? Wv : Wo;
        float4 v = ((const float4*)W)[i];
        ((short4*)(Wb + ((size_t)wsel << 20)))[i] =
            make_short4((short)f2bf(v.x), (short)f2bf(v.y),
                        (short)f2bf(v.z), (short)f2bf(v.w));
    } else if (blk < 8448) {                     // er[64][1024] -> ErT[1024][64]
        int idx = (blk - 8192) * 256 + tid;
        int w = idx >> 6, d = idx & 63;
        ErT[idx] = (short)f2bf(er[d * 1024 + w]);
    } else {                                     // biases: 4 x 1024
        int idx = (blk - 8448) * 256 + tid;
        int sel = idx >> 10, j = idx & 1023;
        const float* s = (sel == 0) ? bq : (sel == 1) ? bk : (sel == 2) ? bv : bo;
        ball[idx] = (short)f2bf(s[j]);
    }
}

// ---------- legacy GEMM body (m97-style 128x128) — still used by out_gemm ----------
__device__ __forceinline__ void gemm_body(
    const short* __restrict__ A, const short* __restrict__ Wt,
    const short* __restrict__ bias, short* __restrict__ dst,
    float* __restrict__ dstf, int variant)
{
    __shared__ short As[128 * 64];
    __shared__ short Bs[128 * 64];
    const int tid  = threadIdx.x;
    const int wid  = tid >> 6;
    const int lane = tid & 63;
    const int m0 = blockIdx.x * 128;
    const int n0 = blockIdx.y * 128;
    const int wm = (wid >> 1) * 64;
    const int wn = (wid & 1) * 64;
    const int lrow = lane & 15;
    const int quad = lane >> 4;
    const int srow = lane >> 3;
    const int sscol = (((lane & 7) ^ (srow & 7)) << 3);
    const int rx = lrow & 7;

    floatx4 acc[4][4];
#pragma unroll
    for (int r = 0; r < 4; ++r)
#pragma unroll
        for (int c = 0; c < 4; ++c) acc[r][c] = (floatx4){0.f, 0.f, 0.f, 0.f};

    for (int k0 = 0; k0 < 1024; k0 += 64) {
#pragma unroll
        for (int i = 0; i < 4; ++i) {
            int q = wid * 4 + i;
            gll16(A + (size_t)(m0 + q * 8 + srow) * 1024 + k0 + sscol,
                  &As[q * 512 + lane * 8]);
        }
#pragma unroll
        for (int i = 0; i < 4; ++i) {
            int q = wid * 4 + i;
            gll16(Wt + (size_t)(n0 + q * 8 + srow) * 1024 + k0 + sscol,
                  &Bs[q * 512 + lane * 8]);
        }
        __syncthreads();
#pragma unroll
        for (int ks = 0; ks < 2; ++ks) {
            short8 af[4], bfr[4];
#pragma unroll
            for (int r = 0; r < 4; ++r)
                af[r] = *(const short8*)&As[(wm + r * 16 + lrow) * 64 +
                                            (((ks * 4 + quad) ^ rx) << 3)];
#pragma unroll
            for (int c = 0; c < 4; ++c)
                bfr[c] = *(const short8*)&Bs[(wn + c * 16 + lrow) * 64 +
                                             (((ks * 4 + quad) ^ rx) << 3)];
#pragma unroll
            for (int r = 0; r < 4; ++r)
#pragma unroll
                for (int c = 0; c < 4; ++c)
                    acc[r][c] = mfma16(af[r], bfr[c], acc[r][c]);
        }
        __syncthreads();
    }

#pragma unroll
    for (int c = 0; c < 4; ++c) {
        int col = n0 + wn + c * 16 + lrow;
        float bv = bf2f((uint16_t)bias[col]);
#pragma unroll
        for (int r = 0; r < 4; ++r) {
#pragma unroll
            for (int g = 0; g < 4; ++g) {
                int m = m0 + wm + r * 16 + quad * 4 + g;
                float fv = acc[r][c][g] + bv;
                if (variant == 3) {
                    dstf[(size_t)m * 1024 + col] = fv;
                } else if (variant == 2) {
                    int bh = (m >> 10) * 16 + (col >> 6);
                    dst[(size_t)bh * 65536 + (size_t)(col & 63) * 1024 + (m & 1023)] =
                        (short)f2bf(fv);
                } else {
                    int bh = (m >> 10) * 16 + (col >> 6);
                    dst[(size_t)bh * 65536 + (size_t)(m & 1023) * 64 + (col & 63)] =
                        (short)f2bf(fv);
                }
            }
        }
    }
}

__global__ __launch_bounds__(256) void out_gemm(
    const short* __restrict__ AV, const short* __restrict__ Wo,
    const short* __restrict__ bo, float* __restrict__ out)
{
    gemm_body(AV, Wo, bo, nullptr, out, 3);
}

// ---------- fused QKV GEMM: 256x256 tile, BK=64, 8-phase counted-vmcnt ----------
// C[4096 x 3072] = xb @ (Wq|Wk|Wv)^T + ball, split to Q/K layout or V^T by n0>>10.
// 8 waves (2M x 4N), wave tile 128x64, acc[8][4]. LDS 128 KiB:
//   per matrix: 2 buf x 2 half(128x64) (A halves = M, B halves = N).
// Iteration i computes tile T0=2i (buf0, phases P1-4) and T1=2i+1 (buf1, P5-8).
// Quadrant order per tile: (mq0,nq0) (mq0,nq1) (mq1,nq1) (mq1,nq0); B bands b0/b1
// held in regs for the whole tile, A band reloaded at P1/P3 — so per-region last
// ds_read: B* = P2(P6), A* = P3(P7).
// Stage slots (1 half-tile = 2 gll16/thread per phase), each >=1 phase after the
// region's last read, >=3 phases before its deadline:
//   P1: buf1.A0<-t(2i+1)  P2: buf1.A1<-t(2i+1)   [deadline P5, guarded by P4 wait]
//   P3: buf0.B0<-t(2i+2)  P4: buf0.B1  P5: buf0.A0  P6: buf0.A1 [deadline next P1,
//        guarded by P8 wait]
//   P7: buf1.B0<-t(2i+3)  P8: buf1.B1             [deadline next P5]
// vmcnt(4) at P4/P8 = leave only the 2 newest half-tiles (4 loads) in flight;
// with the barrier this guarantees the needed buffer fully landed for ALL waves.
#define Q8_BAR   asm volatile("s_barrier" ::: "memory")
#define Q8_VM4   asm volatile("s_waitcnt vmcnt(4)" ::: "memory")
#define Q8_VM0   asm volatile("s_waitcnt vmcnt(0)" ::: "memory")

// stage one 128x64 half-tile (row-major src, ld=1024) into an LDS region
__device__ __forceinline__ void stage_half(const short* src, short* region, int tid)
{
    const int lane = tid & 63;
    const int wid  = tid >> 6;
    const int srow = lane >> 3;                      // row & 7 swizzle key
    const int scol = (((lane & 7) ^ srow) << 3);     // swizzled source col (shorts)
#pragma unroll
    for (int round = 0; round < 2; ++round) {
        int r = round * 64 + wid * 8 + srow;
        gll16(src + (size_t)r * 1024 + scol,
              region + round * 4096 + wid * 512 + lane * 8);
    }
}

#define SA(buf, h) (As + ((buf) * 2 + (h)) * 8192)
#define SB(buf, h) (Bs + ((buf) * 2 + (h)) * 8192)
#define STAGE_A(buf, h, kt) stage_half(Asrc + (size_t)(h) * 131072 + (size_t)(kt) * 64, SA(buf, h), tid)
#define STAGE_B(buf, h, kt) stage_half(Bsrc + (size_t)(h) * 131072 + (size_t)(kt) * 64, SB(buf, h), tid)

#define READ_A(buf, MQ) do { const short* Rp_ = SA(buf, wm); \
    _Pragma("unroll") for (int r_ = 0; r_ < 4; ++r_) { \
        int row_ = (MQ) * 64 + r_ * 16 + lrow; \
        _Pragma("unroll") for (int ks_ = 0; ks_ < 2; ++ks_) \
            a[r_][ks_] = *(const short8*)&Rp_[row_ * 64 + (((ks_ * 4 + quad) ^ rx) << 3)]; \
    } } while (0)

#define READ_B(buf, NQ, BB) do { const short* Rp_ = SB(buf, wn >> 1); \
    _Pragma("unroll") for (int c_ = 0; c_ < 2; ++c_) { \
        int row_ = (wn & 1) * 64 + (NQ) * 32 + c_ * 16 + lrow; \
        _Pragma("unroll") for (int ks_ = 0; ks_ < 2; ++ks_) \
            BB[c_][ks_] = *(const short8*)&Rp_[row_ * 64 + (((ks_ * 4 + quad) ^ rx) << 3)]; \
    } } while (0)

#define MFMA_QUAD(MQ, NQ, BB) do { \
    __builtin_amdgcn_s_setprio(1); \
    _Pragma("unroll") for (int ks_ = 0; ks_ < 2; ++ks_) \
        _Pragma("unroll") for (int r_ = 0; r_ < 4; ++r_) \
            _Pragma("unroll") for (int c_ = 0; c_ < 2; ++c_) \
                acc[(MQ) * 4 + r_][(NQ) * 2 + c_] = \
                    mfma16(a[r_][ks_], BB[c_][ks_], acc[(MQ) * 4 + r_][(NQ) * 2 + c_]); \
    __builtin_amdgcn_s_setprio(0); \
    } while (0)

__global__ __launch_bounds__(512, 2) void qkv_gemm256(
    const short* __restrict__ x, const short* __restrict__ Wb,
    const short* __restrict__ ball,
    short* __restrict__ Qb, short* __restrict__ Kb, short* __restrict__ Vb)
{
    extern __shared__ short lds[];
    short* As = lds;            // 2*2*8192 shorts = 64 KiB
    short* Bs = lds + 32768;    // 64 KiB
    const int tid  = threadIdx.x;
    const int wid  = tid >> 6;
    const int lane = tid & 63;
    const int wm   = wid >> 2;          // 0..1  (M warp)
    const int wn   = wid & 3;           // 0..3  (N warp)
    const int lrow = lane & 15;
    const int quad = lane >> 4;
    const int rx   = lrow & 7;
    const int m0 = blockIdx.x * 256;
    const int n0 = blockIdx.y * 256;
    const short* Asrc = x  + (size_t)m0 * 1024;
    const short* Bsrc = Wb + (size_t)n0 * 1024;

    floatx4 acc[8][4];
#pragma unroll
    for (int r = 0; r < 8; ++r)
#pragma unroll
        for (int c = 0; c < 4; ++c) acc[r][c] = (floatx4){0.f, 0.f, 0.f, 0.f};

    short8 a[4][2], b0[2][2], b1[2][2];

    // prologue: buf0 <- tile0 (all 4 halves), buf1.B <- tile1.
    STAGE_A(0, 0, 0); STAGE_A(0, 1, 0); STAGE_B(0, 0, 0); STAGE_B(0, 1, 0);
    STAGE_B(1, 0, 1); STAGE_B(1, 1, 1);
    Q8_VM4;            // buf0's 8 loads (oldest) landed; buf1.B may be in flight
    Q8_BAR;

#pragma unroll 1
    for (int i = 0; i < 7; ++i) {
        const int t1 = 2 * i + 1, s0 = 2 * i + 2, s1 = 2 * i + 3;
        // ---- tile T0 = 2i from buf0 ----
        // P1
        READ_A(0, 0); READ_B(0, 0, b0);
        STAGE_A(1, 0, t1);
        Q8_BAR; MFMA_QUAD(0, 0, b0); Q8_BAR;
        // P2
        READ_B(0, 1, b1);
        STAGE_A(1, 1, t1);
        Q8_BAR; MFMA_QUAD(0, 1, b1); Q8_BAR;
        // P3
        READ_A(0, 1);
        STAGE_B(0, 0, s0);
        Q8_BAR; MFMA_QUAD(1, 1, b1); Q8_BAR;
        // P4
        STAGE_B(0, 1, s0);
        Q8_VM4;          // buf1 (tile 2i+1) fully landed after barrier
        Q8_BAR; MFMA_QUAD(1, 0, b0); Q8_BAR;
        // ---- tile T1 = 2i+1 from buf1 ----
        // P5
        READ_A(1, 0); READ_B(1, 0, b0);
        STAGE_A(0, 0, s0);
        Q8_BAR; MFMA_QUAD(0, 0, b0); Q8_BAR;
        // P6
        READ_B(1, 1, b1);
        STAGE_A(0, 1, s0);
        Q8_BAR; MFMA_QUAD(0, 1, b1); Q8_BAR;
        // P7
        READ_A(1, 1);
        STAGE_B(1, 0, s1);
        Q8_BAR; MFMA_QUAD(1, 1, b1); Q8_BAR;
        // P8
        STAGE_B(1, 1, s1);
        Q8_VM4;          // buf0 (tile 2i+2) fully landed after barrier
        Q8_BAR; MFMA_QUAD(1, 0, b0); Q8_BAR;
    }

    // tail: tiles 14 (buf0, fully staged) and 15 (buf1: B staged, A here)
    STAGE_A(1, 0, 15); STAGE_A(1, 1, 15);
    Q8_VM4;            // buf0 complete (older than the 4 loads left in flight)
    Q8_BAR;
    READ_A(0, 0); READ_B(0, 0, b0); READ_B(0, 1, b1);
    MFMA_QUAD(0, 0, b0); MFMA_QUAD(0, 1, b1);
    READ_A(0, 1);
    MFMA_QUAD(1, 0, b0); MFMA_QUAD(1, 1, b1);
    Q8_VM0;            // buf1 (tile 15) complete
    Q8_BAR;
    READ_A(1, 0); READ_B(1, 0, b0); READ_B(1, 1, b1);
    MFMA_QUAD(0, 0, b0); MFMA_QUAD(0, 1, b1);
    READ_A(1, 1);
    MFMA_QUAD(1, 0, b0); MFMA_QUAD(1, 1, b1);

    // epilogue: bias add + layout-specific bf16 store
    const int z = n0 >> 10;                          // 0=Q 1=K 2=V
    short* dst = (z == 0) ? Qb : (z == 1) ? Kb : Vb;
#pragma unroll
    for (int fc = 0; fc < 4; ++fc) {
        int col = n0 + wn * 64 + fc * 16 + lrow;     // 0..3071
        int c1  = col & 1023;
        float bv = bf2f((uint16_t)ball[col]);
#pragma unroll
        for (int fr = 0; fr < 8; ++fr) {
#pragma unroll
            for (int g = 0; g < 4; ++g) {
                int m = m0 + wm * 128 + fr * 16 + quad * 4 + g;
                float fv = acc[fr][fc][g] + bv;
                int bh = (m >> 10) * 16 + (c1 >> 6);
                if (z == 2)   // V^T: [b,h,d=64,w=1024]
                    dst[(size_t)bh * 65536 + (size_t)(c1 & 63) * 1024 + (m & 1023)] =
                        (short)f2bf(fv);
                else          // Q/K: [b,h,w=1024,d=64]
                    dst[(size_t)bh * 65536 + (size_t)(m & 1023) * 64 + (c1 & 63)] =
                        (short)f2bf(fv);
            }
        }
    }
}

// ---------- flash attention, double-buffered + swizzled + NO-MAX softmax ----------
#define PSTR 72   // Ps row stride (shorts): 16B-aligned, 4-way max on writes
__global__ __launch_bounds__(512) void attn_kernel(
    const short* __restrict__ Q, const short* __restrict__ K,
    const short* __restrict__ Vt, const short* __restrict__ ErT,
    short* __restrict__ AV)
{
    __shared__ short Ks [2][64 * 64];
    __shared__ short Qks[2][64 * 64];
    __shared__ short Vs [2][64 * 64];
    __shared__ short Ps [128 * PSTR];
    const int tid  = threadIdx.x;
    const int wid  = tid >> 6;
    const int lane = tid & 63;
    const int lrow = lane & 15;
    const int quad = lane >> 4;
    const int lk   = quad * 8;
    const int srow = lane >> 3;
    const int sscol = (((lane & 7) ^ (srow & 7)) << 3);
    const int rx = lrow & 7;
    const int h = blockIdx.x, b = blockIdx.y;
    const int bh = b * 16 + h;
    const int i0 = blockIdx.z * 128;
    const int wrow = wid * 16;
    const short* Qbh = Q  + (size_t)bh * 65536;
    const short* Kbh = K  + (size_t)bh * 65536;
    const short* Vbh = Vt + (size_t)bh * 65536;

    short8 qa[4];
    {
        int row = i0 + wrow + lrow;
#pragma unroll
        for (int kk = 0; kk < 2; ++kk) {
            qa[kk]     = *(const short8*)&Qbh[(size_t)row * 64 + kk * 32 + lk];
            qa[kk + 2] = *(const short8*)&ErT[(size_t)row * 64 + kk * 32 + lk];
        }
    }

    float lrun[4];
    floatx4 oacc[4];
#pragma unroll
    for (int g = 0; g < 4; ++g) lrun[g] = 0.f;
#pragma unroll
    for (int c = 0; c < 4; ++c) oacc[c] = (floatx4){0.f, 0.f, 0.f, 0.f};

    {
        gll16(Kbh + (size_t)(wid * 8 + srow) * 64 + sscol,    &Ks [0][wid * 512 + lane * 8]);
        gll16(Qbh + (size_t)(wid * 8 + srow) * 64 + sscol,    &Qks[0][wid * 512 + lane * 8]);
        gll16(Vbh + (size_t)(wid * 8 + srow) * 1024 + sscol,  &Vs [0][wid * 512 + lane * 8]);
    }

    const float sc2 = 1.44269504088896f / 32.0f;

    for (int jt = 0; jt < 16; ++jt) {
        const int cur = jt & 1;
        __syncthreads();

        if (jt < 15) {
            int j1 = (jt + 1) * 64;
            gll16(Kbh + (size_t)(j1 + wid * 8 + srow) * 64 + sscol,    &Ks [cur ^ 1][wid * 512 + lane * 8]);
            gll16(Qbh + (size_t)(j1 + wid * 8 + srow) * 64 + sscol,    &Qks[cur ^ 1][wid * 512 + lane * 8]);
            gll16(Vbh + (size_t)(wid * 8 + srow) * 1024 + j1 + sscol,  &Vs [cur ^ 1][wid * 512 + lane * 8]);
        }

        floatx4 s[4];
#pragma unroll
        for (int c = 0; c < 4; ++c) s[c] = (floatx4){0.f, 0.f, 0.f, 0.f};
#pragma unroll
        for (int kk = 0; kk < 4; ++kk) {
            short8 kb[4];
#pragma unroll
            for (int c = 0; c < 4; ++c) {
                int kl = (kk < 2) ? kk : kk - 2;
                const short* src = (kk < 2) ? Ks[cur] : Qks[cur];
                kb[c] = *(const short8*)&src[(c * 16 + lrow) * 64 +
                                             (((kl * 4 + quad) ^ rx) << 3)];
            }
#pragma unroll
            for (int c = 0; c < 4; ++c)
                s[c] = mfma16(qa[kk], kb[c], s[c]);
        }

#pragma unroll
        for (int c = 0; c < 4; ++c)
#pragma unroll
            for (int g = 0; g < 4; ++g)
                s[c][g] = exp2f(s[c][g] * sc2);
#pragma unroll
        for (int g = 0; g < 4; ++g) {
            float rs = (s[0][g] + s[1][g]) + (s[2][g] + s[3][g]);
#pragma unroll
            for (int d = 1; d < 16; d <<= 1) rs += __shfl_xor(rs, d, 64);
            lrun[g] += rs;
        }

#pragma unroll
        for (int c = 0; c < 4; ++c)
#pragma unroll
            for (int g = 0; g < 4; ++g)
                Ps[(wrow + quad * 4 + g) * PSTR + c * 16 + lrow] = (short)f2bf(s[c][g]);
        __asm__ __volatile__("" ::: "memory");

#pragma unroll
        for (int kk = 0; kk < 2; ++kk) {
            short8 pa, vb[4];
            pa = *(const short8*)&Ps[(wrow + lrow) * PSTR + kk * 32 + lk];
#pragma unroll
            for (int c = 0; c < 4; ++c)
                vb[c] = *(const short8*)&Vs[cur][(c * 16 + lrow) * 64 +
                                                 (((kk * 4 + quad) ^ rx) << 3)];
#pragma unroll
            for (int c = 0; c < 4; ++c)
                oacc[c] = mfma16(pa, vb[c], oacc[c]);
        }
    }

#pragma unroll
    for (int c = 0; c < 4; ++c)
#pragma unroll
        for (int g = 0; g < 4; ++g) {
            int row = i0 + wrow + quad * 4 + g;
            int colc = h * 64 + c * 16 + lrow;
            AV[((size_t)b * 1024 + row) * 1024 + colc] = (short)f2bf(oacc[c][g] / lrun[g]);
        }
}

// ---------- launcher ----------
extern "C" void kernel_launch(void* const* d_in, const int* in_sizes, int n_in,
                              void* d_out, int out_size, void* d_ws, size_t ws_size,
                              hipStream_t stream) {
    const float* x  = (const float*)d_in[0];
    const float* Wq = (const float*)d_in[1];
    const float* bq = (const float*)d_in[2];
    const float* Wk = (const float*)d_in[3];
    const float* bk = (const float*)d_in[4];
    const float* Wv = (const float*)d_in[5];
    const float* bv = (const float*)d_in[6];
    const float* Wo = (const float*)d_in[7];
    const float* bo = (const float*)d_in[8];
    const float* er = (const float*)d_in[9];
    float* out = (float*)d_out;

    const size_t M1 = 1u << 20;
    short* ws   = (short*)d_ws;
    short* xb   = (short*)d_out;      // bf16 x in d_out's first 8MB; dead before out_gemm
    short* Qb   = ws;                 // 4M  [b,h,w,d]
    short* Kb   = ws + 4 * M1;        // 4M  [b,h,w,d]
    short* Vb   = ws + 8 * M1;        // 4M  [b,h,d,w]
    short* AVb  = ws + 12 * M1;       // 4M  [b,w,c]
    short* Wb   = ws + 16 * M1;       // 4M  (Wq|Wk|Wv|Wo bf16, contiguous)
    short* ball = ws + 20 * M1;       // 4x1024 (bq,bk,bv,bo)
    short* ErT  = ws + 20 * M1 + 4096; // 65536 [w,d]

    static bool attr_done = false;
    if (!attr_done) {
        hipFuncSetAttribute((const void*)qkv_gemm256,
                            hipFuncAttributeMaxDynamicSharedMemorySize, 131072);
        attr_done = true;
    }

    hipLaunchKernelGGL(conv_all, dim3(8464), dim3(256), 0, stream,
                       x, Wq, Wk, Wv, Wo, bq, bk, bv, bo, er, xb, Wb, ball, ErT);
    hipLaunchKernelGGL(qkv_gemm256, dim3(16, 12), dim3(512), 131072, stream,
                       xb, Wb, ball, Qb, Kb, Vb);
    hipLaunchKernelGGL(attn_kernel, dim3(16, 4, 8), dim3(512), 0, stream,
                       Qb, Kb, Vb, ErT, AVb);
    hipLaunchKernelGGL(out_gemm, dim3(32, 8), dim3(256), 0, stream,
                       AVb, Wb + 3 * M1, ball + 3072, out);
}

// Round 2
// 214.845 us; speedup vs baseline: 1.0128x; 1.0128x over previous
//
#include <hip/hip_runtime.h>
#include <stdint.h>

// ---------- types / helpers ----------
typedef __attribute__((ext_vector_type(8))) short   short8;   // 8 bf16 (4 VGPRs)
typedef __attribute__((ext_vector_type(8))) __bf16  bf16x8;
typedef __attribute__((ext_vector_type(4))) float   floatx4;

__device__ __forceinline__ float bf2f(uint16_t h) {
    union { uint32_t u; float f; } v; v.u = ((uint32_t)h) << 16; return v.f;
}
__device__ __forceinline__ uint16_t f2bf(float f) {
    union { float f; uint32_t u; } v; v.f = f;
    uint32_t u = v.u;
    u += 0x7FFFu + ((u >> 16) & 1u);   // RNE
    return (uint16_t)(u >> 16);
}
__device__ __forceinline__ floatx4 mfma16(short8 a, short8 b, floatx4 c) {
    return __builtin_amdgcn_mfma_f32_16x16x32_bf16(
        __builtin_bit_cast(bf16x8, a), __builtin_bit_cast(bf16x8, b), c, 0, 0, 0);
}
// async global->LDS, 16B per lane
__device__ __forceinline__ void gll16(const short* g, short* l) {
    __builtin_amdgcn_global_load_lds(
        (const __attribute__((address_space(1))) uint32_t*)g,
        (__attribute__((address_space(3))) uint32_t*)l, 16, 0, 0);
}
// XOR bank swizzle: physical 16B-group = logical group ^ (row & 7).
// Applied to the GLOBAL source column during staging and to the group index
// on LDS reads. Kills the 128B-row-stride 16-way conflict. [R12: 1.94e7->5e5]

// ---------- merged f32->bf16 conversion (x, 4 weights, 4 biases, er^T) ----------
__global__ void conv_all(
    const float* __restrict__ x,
    const float* __restrict__ Wq, const float* __restrict__ Wk,
    const float* __restrict__ Wv, const float* __restrict__ Wo,
    const float* __restrict__ bq, const float* __restrict__ bk,
    const float* __restrict__ bv, const float* __restrict__ bo,
    const float* __restrict__ er,
    short* __restrict__ xb, short* __restrict__ Wb,
    short* __restrict__ ball, short* __restrict__ ErT)
{
    int blk = blockIdx.x, tid = threadIdx.x;
    if (blk < 4096) {                            // x: 1M float4
        int i = blk * 256 + tid;
        float4 v = ((const float4*)x)[i];
        ((short4*)xb)[i] = make_short4((short)f2bf(v.x), (short)f2bf(v.y),
                                       (short)f2bf(v.z), (short)f2bf(v.w));
    } else if (blk < 8192) {                     // weights: 4 x 256K float4
        int rel = blk - 4096;
        int wsel = rel >> 10;
        int i = (rel & 1023) * 256 + tid;
        const float* W = (wsel == 0) ? Wq : (wsel == 1) ? Wk : (wsel == 2) ? Wv : Wo;
        float4 v = ((const float4*)W)[i];
        ((short4*)(Wb + ((size_t)wsel << 20)))[i] =
            make_short4((short)f2bf(v.x), (short)f2bf(v.y),
                        (short)f2bf(v.z), (short)f2bf(v.w));
    } else if (blk < 8448) {                     // er[64][1024] -> ErT[1024][64]
        int idx = (blk - 8192) * 256 + tid;
        int w = idx >> 6, d = idx & 63;
        ErT[idx] = (short)f2bf(er[d * 1024 + w]);
    } else {                                     // biases: 4 x 1024
        int idx = (blk - 8448) * 256 + tid;
        int sel = idx >> 10, j = idx & 1023;
        const float* s = (sel == 0) ? bq : (sel == 1) ? bk : (sel == 2) ? bv : bo;
        ball[idx] = (short)f2bf(s[j]);
    }
}

// ---------- legacy GEMM body (m97-style 128x128) — still used by out_gemm ----------
__device__ __forceinline__ void gemm_body(
    const short* __restrict__ A, const short* __restrict__ Wt,
    const short* __restrict__ bias, short* __restrict__ dst,
    float* __restrict__ dstf, int variant)
{
    __shared__ short As[128 * 64];
    __shared__ short Bs[128 * 64];
    const int tid  = threadIdx.x;
    const int wid  = tid >> 6;
    const int lane = tid & 63;
    const int m0 = blockIdx.x * 128;
    const int n0 = blockIdx.y * 128;
    const int wm = (wid >> 1) * 64;
    const int wn = (wid & 1) * 64;
    const int lrow = lane & 15;
    const int quad = lane >> 4;
    const int srow = lane >> 3;
    const int sscol = (((lane & 7) ^ (srow & 7)) << 3);
    const int rx = lrow & 7;

    floatx4 acc[4][4];
#pragma unroll
    for (int r = 0; r < 4; ++r)
#pragma unroll
        for (int c = 0; c < 4; ++c) acc[r][c] = (floatx4){0.f, 0.f, 0.f, 0.f};

    for (int k0 = 0; k0 < 1024; k0 += 64) {
#pragma unroll
        for (int i = 0; i < 4; ++i) {
            int q = wid * 4 + i;
            gll16(A + (size_t)(m0 + q * 8 + srow) * 1024 + k0 + sscol,
                  &As[q * 512 + lane * 8]);
        }
#pragma unroll
        for (int i = 0; i < 4; ++i) {
            int q = wid * 4 + i;
            gll16(Wt + (size_t)(n0 + q * 8 + srow) * 1024 + k0 + sscol,
                  &Bs[q * 512 + lane * 8]);
        }
        __syncthreads();
#pragma unroll
        for (int ks = 0; ks < 2; ++ks) {
            short8 af[4], bfr[4];
#pragma unroll
            for (int r = 0; r < 4; ++r)
                af[r] = *(const short8*)&As[(wm + r * 16 + lrow) * 64 +
                                            (((ks * 4 + quad) ^ rx) << 3)];
#pragma unroll
            for (int c = 0; c < 4; ++c)
                bfr[c] = *(const short8*)&Bs[(wn + c * 16 + lrow) * 64 +
                                             (((ks * 4 + quad) ^ rx) << 3)];
#pragma unroll
            for (int r = 0; r < 4; ++r)
#pragma unroll
                for (int c = 0; c < 4; ++c)
                    acc[r][c] = mfma16(af[r], bfr[c], acc[r][c]);
        }
        __syncthreads();
    }

#pragma unroll
    for (int c = 0; c < 4; ++c) {
        int col = n0 + wn + c * 16 + lrow;
        float bv = bf2f((uint16_t)bias[col]);
#pragma unroll
        for (int r = 0; r < 4; ++r) {
#pragma unroll
            for (int g = 0; g < 4; ++g) {
                int m = m0 + wm + r * 16 + quad * 4 + g;
                float fv = acc[r][c][g] + bv;
                if (variant == 3) {
                    dstf[(size_t)m * 1024 + col] = fv;
                } else if (variant == 2) {
                    int bh = (m >> 10) * 16 + (col >> 6);
                    dst[(size_t)bh * 65536 + (size_t)(col & 63) * 1024 + (m & 1023)] =
                        (short)f2bf(fv);
                } else {
                    int bh = (m >> 10) * 16 + (col >> 6);
                    dst[(size_t)bh * 65536 + (size_t)(m & 1023) * 64 + (col & 63)] =
                        (short)f2bf(fv);
                }
            }
        }
    }
}

__global__ __launch_bounds__(256) void out_gemm(
    const short* __restrict__ AV, const short* __restrict__ Wo,
    const short* __restrict__ bo, float* __restrict__ out)
{
    gemm_body(AV, Wo, bo, nullptr, out, 3);
}

// ---------- fused QKV GEMM: 256x256 tile, BK=64, 8-phase counted-vmcnt ----------
// C[4096 x 3072] = xb @ (Wq|Wk|Wv)^T + ball, split to Q/K layout or V^T by n0>>10.
// 8 waves (2M x 4N), wave tile 128x64, acc[8][4]. LDS 128 KiB.
// R2 RESTRUCTURE (cross-barrier read pipelining): each phase's ds_reads now load
// the operands for the NEXT phase and are issued AFTER the current MFMA cluster.
// At MFMA time a wave has ZERO outstanding ds ops (reads completed during the
// previous barrier windows + partner-wave MFMA), so the compiler's lgkmcnt wait
// is trivially satisfied and the LDS-read time no longer adds serially to the
// MFMA time inside each barrier segment. [R1 post-mortem: phases measured
// ~2200cyc = t_LDS + t_MFMA serial; target ~1400]
// Consumer->reader map (a aliased across quadrants, WAR-safe in program order):
//   a0=A(q0) read P8prev (used P1,P2) ; b0=B(q0) read P8prev (used P1,P4)
//   b1=B(q1) read P1 (used P2,P3)    ; a1=A(q1) read P2 (used P3,P4)
//   buf1 set read P4/P5/P6 (after P4's vm4+bar) ; buf0' set read P8 (after vm4+bar)
// Stage slots & vmcnt accounting UNCHANGED from R1 (verified):
//   P1/P2: buf1.A<-t(2i+1); P3..P6: buf0<-t(2i+2); P7/P8: buf1.B<-t(2i+3)
//   vm4 @P4: drains prevP7..P2 -> buf1(t 2i+1) complete before its reads @P4.
//   vm4 @P8: drains P3..P6    -> buf0(t 2i+2) complete before its reads @P8.
#define Q8_BAR   asm volatile("s_barrier" ::: "memory")
#define Q8_VM4   asm volatile("s_waitcnt vmcnt(4)" ::: "memory")
#define Q8_VM0   asm volatile("s_waitcnt vmcnt(0)" ::: "memory")

// stage one 128x64 half-tile (row-major src, ld=1024) into an LDS region
__device__ __forceinline__ void stage_half(const short* src, short* region, int tid)
{
    const int lane = tid & 63;
    const int wid  = tid >> 6;
    const int srow = lane >> 3;                      // row & 7 swizzle key
    const int scol = (((lane & 7) ^ srow) << 3);     // swizzled source col (shorts)
#pragma unroll
    for (int round = 0; round < 2; ++round) {
        int r = round * 64 + wid * 8 + srow;
        gll16(src + (size_t)r * 1024 + scol,
              region + round * 4096 + wid * 512 + lane * 8);
    }
}

#define SA(buf, h) (As + ((buf) * 2 + (h)) * 8192)
#define SB(buf, h) (Bs + ((buf) * 2 + (h)) * 8192)
#define STAGE_A(buf, h, kt) stage_half(Asrc + (size_t)(h) * 131072 + (size_t)(kt) * 64, SA(buf, h), tid)
#define STAGE_B(buf, h, kt) stage_half(Bsrc + (size_t)(h) * 131072 + (size_t)(kt) * 64, SB(buf, h), tid)

#define READ_A(buf, MQ) do { const short* Rp_ = SA(buf, wm); \
    _Pragma("unroll") for (int r_ = 0; r_ < 4; ++r_) { \
        int row_ = (MQ) * 64 + r_ * 16 + lrow; \
        _Pragma("unroll") for (int ks_ = 0; ks_ < 2; ++ks_) \
            a[r_][ks_] = *(const short8*)&Rp_[row_ * 64 + (((ks_ * 4 + quad) ^ rx) << 3)]; \
    } } while (0)

#define READ_B(buf, NQ, BB) do { const short* Rp_ = SB(buf, wn >> 1); \
    _Pragma("unroll") for (int c_ = 0; c_ < 2; ++c_) { \
        int row_ = (wn & 1) * 64 + (NQ) * 32 + c_ * 16 + lrow; \
        _Pragma("unroll") for (int ks_ = 0; ks_ < 2; ++ks_) \
            BB[c_][ks_] = *(const short8*)&Rp_[row_ * 64 + (((ks_ * 4 + quad) ^ rx) << 3)]; \
    } } while (0)

#define MFMA_QUAD(MQ, NQ, BB) do { \
    __builtin_amdgcn_s_setprio(1); \
    _Pragma("unroll") for (int ks_ = 0; ks_ < 2; ++ks_) \
        _Pragma("unroll") for (int r_ = 0; r_ < 4; ++r_) \
            _Pragma("unroll") for (int c_ = 0; c_ < 2; ++c_) \
                acc[(MQ) * 4 + r_][(NQ) * 2 + c_] = \
                    mfma16(a[r_][ks_], BB[c_][ks_], acc[(MQ) * 4 + r_][(NQ) * 2 + c_]); \
    __builtin_amdgcn_s_setprio(0); \
    } while (0)

__global__ __launch_bounds__(512, 2) void qkv_gemm256(
    const short* __restrict__ x, const short* __restrict__ Wb,
    const short* __restrict__ ball,
    short* __restrict__ Qb, short* __restrict__ Kb, short* __restrict__ Vb)
{
    extern __shared__ short lds[];
    short* As = lds;            // 2*2*8192 shorts = 64 KiB
    short* Bs = lds + 32768;    // 64 KiB
    const int tid  = threadIdx.x;
    const int wid  = tid >> 6;
    const int lane = tid & 63;
    const int wm   = wid >> 2;          // 0..1  (M warp)
    const int wn   = wid & 3;           // 0..3  (N warp)
    const int lrow = lane & 15;
    const int quad = lane >> 4;
    const int rx   = lrow & 7;
    const int m0 = blockIdx.x * 256;
    const int n0 = blockIdx.y * 256;
    const short* Asrc = x  + (size_t)m0 * 1024;
    const short* Bsrc = Wb + (size_t)n0 * 1024;

    floatx4 acc[8][4];
#pragma unroll
    for (int r = 0; r < 8; ++r)
#pragma unroll
        for (int c = 0; c < 4; ++c) acc[r][c] = (floatx4){0.f, 0.f, 0.f, 0.f};

    short8 a[4][2], b0[2][2], b1[2][2];

    // prologue: buf0 <- tile0 (all 4 halves), buf1.B <- tile1; then pre-read
    // the P1 operands (a0,b0) so the loop enters in pipelined steady state.
    STAGE_A(0, 0, 0); STAGE_A(0, 1, 0); STAGE_B(0, 0, 0); STAGE_B(0, 1, 0);
    STAGE_B(1, 0, 1); STAGE_B(1, 1, 1);
    Q8_VM4;            // buf0's 8 loads (oldest) landed; buf1.B may be in flight
    Q8_BAR;
    READ_A(0, 0); READ_B(0, 0, b0);

#pragma unroll 1
    for (int i = 0; i < 7; ++i) {
        const int t1 = 2 * i + 1, s0 = 2 * i + 2, s1 = 2 * i + 3;
        // ---- tile T0 = 2i from buf0 ----
        // P1
        STAGE_A(1, 0, t1);
        Q8_BAR; MFMA_QUAD(0, 0, b0); READ_B(0, 1, b1); Q8_BAR;
        // P2
        STAGE_A(1, 1, t1);
        Q8_BAR; MFMA_QUAD(0, 1, b1); READ_A(0, 1); Q8_BAR;
        // P3
        STAGE_B(0, 0, s0);
        Q8_BAR; MFMA_QUAD(1, 1, b1); Q8_BAR;
        // P4
        STAGE_B(0, 1, s0);
        Q8_VM4;          // buf1 (tile 2i+1) fully landed after barrier
        Q8_BAR; MFMA_QUAD(1, 0, b0); READ_A(1, 0); READ_B(1, 0, b0); Q8_BAR;
        // ---- tile T1 = 2i+1 from buf1 ----
        // P5
        STAGE_A(0, 0, s0);
        Q8_BAR; MFMA_QUAD(0, 0, b0); READ_B(1, 1, b1); Q8_BAR;
        // P6
        STAGE_A(0, 1, s0);
        Q8_BAR; MFMA_QUAD(0, 1, b1); READ_A(1, 1); Q8_BAR;
        // P7
        STAGE_B(1, 0, s1);
        Q8_BAR; MFMA_QUAD(1, 1, b1); Q8_BAR;
        // P8
        STAGE_B(1, 1, s1);
        Q8_VM4;          // buf0 (tile 2i+2) fully landed after barrier
        Q8_BAR; MFMA_QUAD(1, 0, b0); READ_A(0, 0); READ_B(0, 0, b0); Q8_BAR;
    }

    // tail: tile 14 (buf0, fully staged; a0/b0 pre-read at last P8) then
    // tile 15 (buf1: B staged in loop i=6 P7/P8, A staged here).
    // T1
    STAGE_A(1, 0, 15);
    Q8_BAR; MFMA_QUAD(0, 0, b0); READ_B(0, 1, b1); Q8_BAR;
    // T2
    STAGE_A(1, 1, 15);
    Q8_BAR; MFMA_QUAD(0, 1, b1); READ_A(0, 1); Q8_BAR;
    // T3 (no stage / no reads)
    MFMA_QUAD(1, 1, b1);
    // T4: drain ALL remaining stages (buf1.B from i=6 + buf1.A from T1/T2)
    Q8_VM0;
    Q8_BAR;
    MFMA_QUAD(1, 0, b0); READ_A(1, 0); READ_B(1, 0, b0);
    // T5..T8: buf1 stable, no cross-wave hazards -> barrier-free
    MFMA_QUAD(0, 0, b0); READ_B(1, 1, b1);
    MFMA_QUAD(0, 1, b1); READ_A(1, 1);
    MFMA_QUAD(1, 1, b1);
    MFMA_QUAD(1, 0, b0);

    // epilogue: bias add + layout-specific bf16 store
    const int z = n0 >> 10;                          // 0=Q 1=K 2=V
    short* dst = (z == 0) ? Qb : (z == 1) ? Kb : Vb;
#pragma unroll
    for (int fc = 0; fc < 4; ++fc) {
        int col = n0 + wn * 64 + fc * 16 + lrow;     // 0..3071
        int c1  = col & 1023;
        float bv = bf2f((uint16_t)ball[col]);
#pragma unroll
        for (int fr = 0; fr < 8; ++fr) {
#pragma unroll
            for (int g = 0; g < 4; ++g) {
                int m = m0 + wm * 128 + fr * 16 + quad * 4 + g;
                float fv = acc[fr][fc][g] + bv;
                int bh = (m >> 10) * 16 + (c1 >> 6);
                if (z == 2)   // V^T: [b,h,d=64,w=1024]
                    dst[(size_t)bh * 65536 + (size_t)(c1 & 63) * 1024 + (m & 1023)] =
                        (short)f2bf(fv);
                else          // Q/K: [b,h,w=1024,d=64]
                    dst[(size_t)bh * 65536 + (size_t)(m & 1023) * 64 + (c1 & 63)] =
                        (short)f2bf(fv);
            }
        }
    }
}

// ---------- flash attention, double-buffered + swizzled + NO-MAX softmax ----------
#define PSTR 72   // Ps row stride (shorts): 16B-aligned, 4-way max on writes
__global__ __launch_bounds__(512) void attn_kernel(
    const short* __restrict__ Q, const short* __restrict__ K,
    const short* __restrict__ Vt, const short* __restrict__ ErT,
    short* __restrict__ AV)
{
    __shared__ short Ks [2][64 * 64];
    __shared__ short Qks[2][64 * 64];
    __shared__ short Vs [2][64 * 64];
    __shared__ short Ps [128 * PSTR];
    const int tid  = threadIdx.x;
    const int wid  = tid >> 6;
    const int lane = tid & 63;
    const int lrow = lane & 15;
    const int quad = lane >> 4;
    const int lk   = quad * 8;
    const int srow = lane >> 3;
    const int sscol = (((lane & 7) ^ (srow & 7)) << 3);
    const int rx = lrow & 7;
    const int h = blockIdx.x, b = blockIdx.y;
    const int bh = b * 16 + h;
    const int i0 = blockIdx.z * 128;
    const int wrow = wid * 16;
    const short* Qbh = Q  + (size_t)bh * 65536;
    const short* Kbh = K  + (size_t)bh * 65536;
    const short* Vbh = Vt + (size_t)bh * 65536;

    short8 qa[4];
    {
        int row = i0 + wrow + lrow;
#pragma unroll
        for (int kk = 0; kk < 2; ++kk) {
            qa[kk]     = *(const short8*)&Qbh[(size_t)row * 64 + kk * 32 + lk];
            qa[kk + 2] = *(const short8*)&ErT[(size_t)row * 64 + kk * 32 + lk];
        }
    }

    float lrun[4];
    floatx4 oacc[4];
#pragma unroll
    for (int g = 0; g < 4; ++g) lrun[g] = 0.f;
#pragma unroll
    for (int c = 0; c < 4; ++c) oacc[c] = (floatx4){0.f, 0.f, 0.f, 0.f};

    {
        gll16(Kbh + (size_t)(wid * 8 + srow) * 64 + sscol,    &Ks [0][wid * 512 + lane * 8]);
        gll16(Qbh + (size_t)(wid * 8 + srow) * 64 + sscol,    &Qks[0][wid * 512 + lane * 8]);
        gll16(Vbh + (size_t)(wid * 8 + srow) * 1024 + sscol,  &Vs [0][wid * 512 + lane * 8]);
    }

    const float sc2 = 1.44269504088896f / 32.0f;

    for (int jt = 0; jt < 16; ++jt) {
        const int cur = jt & 1;
        __syncthreads();

        if (jt < 15) {
            int j1 = (jt + 1) * 64;
            gll16(Kbh + (size_t)(j1 + wid * 8 + srow) * 64 + sscol,    &Ks [cur ^ 1][wid * 512 + lane * 8]);
            gll16(Qbh + (size_t)(j1 + wid * 8 + srow) * 64 + sscol,    &Qks[cur ^ 1][wid * 512 + lane * 8]);
            gll16(Vbh + (size_t)(wid * 8 + srow) * 1024 + j1 + sscol,  &Vs [cur ^ 1][wid * 512 + lane * 8]);
        }

        floatx4 s[4];
#pragma unroll
        for (int c = 0; c < 4; ++c) s[c] = (floatx4){0.f, 0.f, 0.f, 0.f};
#pragma unroll
        for (int kk = 0; kk < 4; ++kk) {
            short8 kb[4];
#pragma unroll
            for (int c = 0; c < 4; ++c) {
                int kl = (kk < 2) ? kk : kk - 2;
                const short* src = (kk < 2) ? Ks[cur] : Qks[cur];
                kb[c] = *(const short8*)&src[(c * 16 + lrow) * 64 +
                                             (((kl * 4 + quad) ^ rx) << 3)];
            }
#pragma unroll
            for (int c = 0; c < 4; ++c)
                s[c] = mfma16(qa[kk], kb[c], s[c]);
        }

#pragma unroll
        for (int c = 0; c < 4; ++c)
#pragma unroll
            for (int g = 0; g < 4; ++g)
                s[c][g] = exp2f(s[c][g] * sc2);
#pragma unroll
        for (int g = 0; g < 4; ++g) {
            float rs = (s[0][g] + s[1][g]) + (s[2][g] + s[3][g]);
#pragma unroll
            for (int d = 1; d < 16; d <<= 1) rs += __shfl_xor(rs, d, 64);
            lrun[g] += rs;
        }

#pragma unroll
        for (int c = 0; c < 4; ++c)
#pragma unroll
            for (int g = 0; g < 4; ++g)
                Ps[(wrow + quad * 4 + g) * PSTR + c * 16 + lrow] = (short)f2bf(s[c][g]);
        __asm__ __volatile__("" ::: "memory");

#pragma unroll
        for (int kk = 0; kk < 2; ++kk) {
            short8 pa, vb[4];
            pa = *(const short8*)&Ps[(wrow + lrow) * PSTR + kk * 32 + lk];
#pragma unroll
            for (int c = 0; c < 4; ++c)
                vb[c] = *(const short8*)&Vs[cur][(c * 16 + lrow) * 64 +
                                                 (((kk * 4 + quad) ^ rx) << 3)];
#pragma unroll
            for (int c = 0; c < 4; ++c)
                oacc[c] = mfma16(pa, vb[c], oacc[c]);
        }
    }

#pragma unroll
    for (int c = 0; c < 4; ++c)
#pragma unroll
        for (int g = 0; g < 4; ++g) {
            int row = i0 + wrow + quad * 4 + g;
            int colc = h * 64 + c * 16 + lrow;
            AV[((size_t)b * 1024 + row) * 1024 + colc] = (short)f2bf(oacc[c][g] / lrun[g]);
        }
}

// ---------- launcher ----------
extern "C" void kernel_launch(void* const* d_in, const int* in_sizes, int n_in,
                              void* d_out, int out_size, void* d_ws, size_t ws_size,
                              hipStream_t stream) {
    const float* x  = (const float*)d_in[0];
    const float* Wq = (const float*)d_in[1];
    const float* bq = (const float*)d_in[2];
    const float* Wk = (const float*)d_in[3];
    const float* bk = (const float*)d_in[4];
    const float* Wv = (const float*)d_in[5];
    const float* bv = (const float*)d_in[6];
    const float* Wo = (const float*)d_in[7];
    const float* bo = (const float*)d_in[8];
    const float* er = (const float*)d_in[9];
    float* out = (float*)d_out;

    const size_t M1 = 1u << 20;
    short* ws   = (short*)d_ws;
    short* xb   = (short*)d_out;      // bf16 x in d_out's first 8MB; dead before out_gemm
    short* Qb   = ws;                 // 4M  [b,h,w,d]
    short* Kb   = ws + 4 * M1;        // 4M  [b,h,w,d]
    short* Vb   = ws + 8 * M1;        // 4M  [b,h,d,w]
    short* AVb  = ws + 12 * M1;       // 4M  [b,w,c]
    short* Wb   = ws + 16 * M1;       // 4M  (Wq|Wk|Wv|Wo bf16, contiguous)
    short* ball = ws + 20 * M1;       // 4x1024 (bq,bk,bv,bo)
    short* ErT  = ws + 20 * M1 + 4096; // 65536 [w,d]

    static bool attr_done = false;
    if (!attr_done) {
        hipFuncSetAttribute((const void*)qkv_gemm256,
                            hipFuncAttributeMaxDynamicSharedMemorySize, 131072);
        attr_done = true;
    }

    hipLaunchKernelGGL(conv_all, dim3(8464), dim3(256), 0, stream,
                       x, Wq, Wk, Wv, Wo, bq, bk, bv, bo, er, xb, Wb, ball, ErT);
    hipLaunchKernelGGL(qkv_gemm256, dim3(16, 12), dim3(512), 131072, stream,
                       xb, Wb, ball, Qb, Kb, Vb);
    hipLaunchKernelGGL(attn_kernel, dim3(16, 4, 8), dim3(512), 0, stream,
                       Qb, Kb, Vb, ErT, AVb);
    hipLaunchKernelGGL(out_gemm, dim3(32, 8), dim3(256), 0, stream,
                       AVb, Wb + 3 * M1, ball + 3072, out);
}

// Round 4
// 209.406 us; speedup vs baseline: 1.0391x; 1.0260x over previous
//
#include <hip/hip_runtime.h>
#include <stdint.h>

// ---------- types / helpers ----------
typedef __attribute__((ext_vector_type(8))) short   short8;   // 8 bf16 (4 VGPRs)
typedef __attribute__((ext_vector_type(8))) __bf16  bf16x8;
typedef __attribute__((ext_vector_type(4))) float   floatx4;

__device__ __forceinline__ float bf2f(uint16_t h) {
    union { uint32_t u; float f; } v; v.u = ((uint32_t)h) << 16; return v.f;
}
__device__ __forceinline__ uint16_t f2bf(float f) {
    union { float f; uint32_t u; } v; v.f = f;
    uint32_t u = v.u;
    u += 0x7FFFu + ((u >> 16) & 1u);   // RNE
    return (uint16_t)(u >> 16);
}
__device__ __forceinline__ floatx4 mfma16(short8 a, short8 b, floatx4 c) {
    return __builtin_amdgcn_mfma_f32_16x16x32_bf16(
        __builtin_bit_cast(bf16x8, a), __builtin_bit_cast(bf16x8, b), c, 0, 0, 0);
}
// async global->LDS, 16B per lane
__device__ __forceinline__ void gll16(const short* g, short* l) {
    __builtin_amdgcn_global_load_lds(
        (const __attribute__((address_space(1))) uint32_t*)g,
        (__attribute__((address_space(3))) uint32_t*)l, 16, 0, 0);
}
// XOR bank swizzle: physical 16B-group = logical group ^ (row & 7).
// Applied to the GLOBAL source column during staging and to the group index
// on LDS reads. Kills the 128B-row-stride 16-way conflict. [R12: 1.94e7->5e5]

// ---------- merged f32->bf16 conversion (x, 4 weights, 4 biases, er^T) ----------
__global__ void conv_all(
    const float* __restrict__ x,
    const float* __restrict__ Wq, const float* __restrict__ Wk,
    const float* __restrict__ Wv, const float* __restrict__ Wo,
    const float* __restrict__ bq, const float* __restrict__ bk,
    const float* __restrict__ bv, const float* __restrict__ bo,
    const float* __restrict__ er,
    short* __restrict__ xb, short* __restrict__ Wb,
    short* __restrict__ ball, short* __restrict__ ErT)
{
    int blk = blockIdx.x, tid = threadIdx.x;
    if (blk < 4096) {                            // x: 1M float4
        int i = blk * 256 + tid;
        float4 v = ((const float4*)x)[i];
        ((short4*)xb)[i] = make_short4((short)f2bf(v.x), (short)f2bf(v.y),
                                       (short)f2bf(v.z), (short)f2bf(v.w));
    } else if (blk < 8192) {                     // weights: 4 x 256K float4
        int rel = blk - 4096;
        int wsel = rel >> 10;
        int i = (rel & 1023) * 256 + tid;
        const float* W = (wsel == 0) ? Wq : (wsel == 1) ? Wk : (wsel == 2) ? Wv : Wo;
        float4 v = ((const float4*)W)[i];
        ((short4*)(Wb + ((size_t)wsel << 20)))[i] =
            make_short4((short)f2bf(v.x), (short)f2bf(v.y),
                        (short)f2bf(v.z), (short)f2bf(v.w));
    } else if (blk < 8448) {                     // er[64][1024] -> ErT[1024][64]
        int idx = (blk - 8192) * 256 + tid;
        int w = idx >> 6, d = idx & 63;
        ErT[idx] = (short)f2bf(er[d * 1024 + w]);
    } else {                                     // biases: 4 x 1024
        int idx = (blk - 8448) * 256 + tid;
        int sel = idx >> 10, j = idx & 1023;
        const float* s = (sel == 0) ? bq : (sel == 1) ? bk : (sel == 2) ? bv : bo;
        ball[idx] = (short)f2bf(s[j]);
    }
}

// ---------- legacy GEMM body (m97-style 128x128) — still used by out_gemm ----------
__device__ __forceinline__ void gemm_body(
    const short* __restrict__ A, const short* __restrict__ Wt,
    const short* __restrict__ bias, short* __restrict__ dst,
    float* __restrict__ dstf, int variant)
{
    __shared__ short As[128 * 64];
    __shared__ short Bs[128 * 64];
    const int tid  = threadIdx.x;
    const int wid  = tid >> 6;
    const int lane = tid & 63;
    const int m0 = blockIdx.x * 128;
    const int n0 = blockIdx.y * 128;
    const int wm = (wid >> 1) * 64;
    const int wn = (wid & 1) * 64;
    const int lrow = lane & 15;
    const int quad = lane >> 4;
    const int srow = lane >> 3;
    const int sscol = (((lane & 7) ^ (srow & 7)) << 3);
    const int rx = lrow & 7;

    floatx4 acc[4][4];
#pragma unroll
    for (int r = 0; r < 4; ++r)
#pragma unroll
        for (int c = 0; c < 4; ++c) acc[r][c] = (floatx4){0.f, 0.f, 0.f, 0.f};

    for (int k0 = 0; k0 < 1024; k0 += 64) {
#pragma unroll
        for (int i = 0; i < 4; ++i) {
            int q = wid * 4 + i;
            gll16(A + (size_t)(m0 + q * 8 + srow) * 1024 + k0 + sscol,
                  &As[q * 512 + lane * 8]);
        }
#pragma unroll
        for (int i = 0; i < 4; ++i) {
            int q = wid * 4 + i;
            gll16(Wt + (size_t)(n0 + q * 8 + srow) * 1024 + k0 + sscol,
                  &Bs[q * 512 + lane * 8]);
        }
        __syncthreads();
#pragma unroll
        for (int ks = 0; ks < 2; ++ks) {
            short8 af[4], bfr[4];
#pragma unroll
            for (int r = 0; r < 4; ++r)
                af[r] = *(const short8*)&As[(wm + r * 16 + lrow) * 64 +
                                            (((ks * 4 + quad) ^ rx) << 3)];
#pragma unroll
            for (int c = 0; c < 4; ++c)
                bfr[c] = *(const short8*)&Bs[(wn + c * 16 + lrow) * 64 +
                                             (((ks * 4 + quad) ^ rx) << 3)];
#pragma unroll
            for (int r = 0; r < 4; ++r)
#pragma unroll
                for (int c = 0; c < 4; ++c)
                    acc[r][c] = mfma16(af[r], bfr[c], acc[r][c]);
        }
        __syncthreads();
    }

#pragma unroll
    for (int c = 0; c < 4; ++c) {
        int col = n0 + wn + c * 16 + lrow;
        float bv = bf2f((uint16_t)bias[col]);
#pragma unroll
        for (int r = 0; r < 4; ++r) {
#pragma unroll
            for (int g = 0; g < 4; ++g) {
                int m = m0 + wm + r * 16 + quad * 4 + g;
                float fv = acc[r][c][g] + bv;
                if (variant == 3) {
                    dstf[(size_t)m * 1024 + col] = fv;
                } else if (variant == 2) {
                    int bh = (m >> 10) * 16 + (col >> 6);
                    dst[(size_t)bh * 65536 + (size_t)(col & 63) * 1024 + (m & 1023)] =
                        (short)f2bf(fv);
                } else {
                    int bh = (m >> 10) * 16 + (col >> 6);
                    dst[(size_t)bh * 65536 + (size_t)(m & 1023) * 64 + (col & 63)] =
                        (short)f2bf(fv);
                }
            }
        }
    }
}

__global__ __launch_bounds__(256) void out_gemm(
    const short* __restrict__ AV, const short* __restrict__ Wo,
    const short* __restrict__ bo, float* __restrict__ out)
{
    gemm_body(AV, Wo, bo, nullptr, out, 3);
}

// ---------- fused QKV GEMM: 256x192 tile, BK=64, grid=256 blocks (ALL CUs) ----------
// R4 = R3 with the B fragment/unit RACE FIXED.
// C[4096 x 3072] = xb @ (Wq|Wk|Wv)^T, tile 256(M) x 192(N) -> grid 16x16 = 256
// blocks = 1/CU. 8 waves (2M x 4N), wave tile 128 x (3 x 16-col slices), acc[8][3].
// Per K-tile (BK=64): 3 phases. Phase c computes the 16-col fragment
// col = c*64 + wn*16 + lrow  ==> PHASE c READS B-UNIT c ONLY (the 4 wn-waves
// tile unit c's 64 rows exactly). [R3 bug: row = wn*48+c*16 straddled units ->
// Ph2/Ph3 read units 0/1 while they were being restaged -> absmax 7.8e-2.]
// A-frags for the whole K-tile are read to REGISTERS in phase c=0 (a[8][2]),
// freeing the A region for restaging from phase c=1 onward.
// LDS 112 KiB: A = 2buf x 4units(64x64), B = 2buf x 3units. Stage unit = 64x64
// subtile = 8KB = one gll16 per thread (512 thr).
// Slot map (iteration i computes tiles E=2i (buf0, Ph1-3) and O=2i+1 (buf1,
// Ph4-6); stages buf0<-2i+2, buf1<-2i+3). Region last-read -> restage phase:
//   Ph1: stage buf1.B2<-2i+1 (old read prev Ph6)      | compute E c=0 (A->regs, B0)
//   Ph2: stage buf0.{A0,A1,B0}<-2i+2 (read Ph1)       | compute E c=1 (B1)
//   Ph3: stage buf0.{A2,A3,B1}<-2i+2 (B1 read Ph2)    | compute E c=2 (B2)
//   Ph4: stage buf0.B2<-2i+2 (read Ph3)               | compute O c=0 (A->regs, B0)
//   Ph5: stage buf1.{A0,A1,B0}<-2i+3 (read Ph4)       | compute O c=1 (B1)
//   Ph6: stage buf1.{A2,A3,B1}<-2i+3 (B1 read Ph5)    | compute O c=2 (B2)
// Every restage is issued AFTER the trailing barrier of the phase that last
// read the unit. Waits: vmcnt(7) in Ph1 (retains {Ph5,Ph6,Ph1}=7 -> completes
// buf0 = prev {Ph2,Ph3,Ph4}) and in Ph4 (retains {Ph2,Ph3,Ph4} -> completes
// buf1 = {prev Ph5, prev Ph6, this Ph1}).
// Grid: bijective XCD swizzle; per XCD: 2 n-tiles (B 0.75MB L2-resident), and
// blocks sharing an A-panel run concurrently on the SAME XCD.
#define VM7  asm volatile("s_waitcnt vmcnt(7)" ::: "memory")
#define VM6  asm volatile("s_waitcnt vmcnt(6)" ::: "memory")
#define VM0  asm volatile("s_waitcnt vmcnt(0)" ::: "memory")
#define BARR asm volatile("s_barrier" ::: "memory")

// stage one 64x64 subtile (row-major src, ld=1024) into an 8KB LDS region
__device__ __forceinline__ void stage_unit(const short* src, short* region, int tid)
{
    const int row  = tid >> 3;                       // 0..63
    const int scol = (((tid & 7) ^ (row & 7)) << 3); // swizzled source col (shorts)
    gll16(src + (size_t)row * 1024 + scol, region + tid * 8);
}

#define SAU(buf, u) (As + (buf) * 16384 + (u) * 4096)
#define SBU(buf, u) (Bs + (buf) * 12288 + (u) * 4096)
#define STG_A(buf, u, kt) stage_unit(Asrc + (size_t)(u) * 65536 + (size_t)(kt) * 64, SAU(buf, u), tid)
#define STG_B(buf, u, kt) stage_unit(Bsrc + (size_t)(u) * 65536 + (size_t)(kt) * 64, SBU(buf, u), tid)

#define RD_A(buf) do { \
    _Pragma("unroll") for (int fr_ = 0; fr_ < 8; ++fr_) { \
        const short* p_ = SAU(buf, wm * 2 + (fr_ >> 2)) + ((fr_ & 3) * 16 + lrow) * 64; \
        _Pragma("unroll") for (int ks_ = 0; ks_ < 2; ++ks_) \
            a[fr_][ks_] = *(const short8*)&p_[((ks_ * 4 + quad) ^ rx) << 3]; \
    } } while (0)

// phase c reads ONLY unit c; wave wn owns rows wn*16..wn*16+15 of that unit
#define RD_B(buf, c) do { \
    const short* p_ = SBU(buf, c) + (wn * 16 + lrow) * 64; \
    _Pragma("unroll") for (int ks_ = 0; ks_ < 2; ++ks_) \
        bb[ks_] = *(const short8*)&p_[((ks_ * 4 + quad) ^ rx) << 3]; \
    } while (0)

#define MFMA_PH(c) do { \
    __builtin_amdgcn_s_setprio(1); \
    _Pragma("unroll") for (int ks_ = 0; ks_ < 2; ++ks_) \
        _Pragma("unroll") for (int fr_ = 0; fr_ < 8; ++fr_) \
            acc[fr_][c] = mfma16(a[fr_][ks_], bb[ks_], acc[fr_][c]); \
    __builtin_amdgcn_s_setprio(0); \
    } while (0)

__global__ __launch_bounds__(512, 2) void qkv_gemm192(
    const short* __restrict__ x, const short* __restrict__ Wb,
    const short* __restrict__ ball,
    short* __restrict__ Qb, short* __restrict__ Kb, short* __restrict__ Vb)
{
    extern __shared__ short lds[];
    short* As = lds;              // 2 buf x 4 units x 4096 shorts = 64 KiB
    short* Bs = lds + 32768;      // 2 buf x 3 units x 4096 shorts = 48 KiB
    const int tid  = threadIdx.x;
    const int wid  = tid >> 6;
    const int lane = tid & 63;
    const int wm   = wid >> 2;          // 0..1  (M warp)
    const int wn   = wid & 3;           // 0..3  (N warp)
    const int lrow = lane & 15;
    const int quad = lane >> 4;
    const int rx   = lrow & 7;
    const int bid  = blockIdx.x;
    const int swz  = (bid & 7) * 32 + (bid >> 3);   // bijective XCD chunking
    const int mi   = swz & 15, ni = swz >> 4;
    const int m0   = mi * 256, n0 = ni * 192;
    const short* Asrc = x  + (size_t)m0 * 1024;
    const short* Bsrc = Wb + (size_t)n0 * 1024;

    floatx4 acc[8][3];
#pragma unroll
    for (int r = 0; r < 8; ++r)
#pragma unroll
        for (int c = 0; c < 3; ++c) acc[r][c] = (floatx4){0.f, 0.f, 0.f, 0.f};

    short8 a[8][2], bb[2];

    // prologue: buf0 <- tile0 (7 units), buf1 <- tile1 (6 units; B2 lands in Ph1)
    STG_A(0, 0, 0); STG_A(0, 1, 0); STG_A(0, 2, 0); STG_A(0, 3, 0);
    STG_B(0, 0, 0); STG_B(0, 1, 0); STG_B(0, 2, 0);
    STG_A(1, 0, 1); STG_A(1, 1, 1); STG_A(1, 2, 1); STG_A(1, 3, 1);
    STG_B(1, 0, 1); STG_B(1, 1, 1);
    VM6; BARR;

#pragma unroll 1
    for (int i = 0; i < 7; ++i) {
        const int t1 = 2 * i + 1, s0 = 2 * i + 2, s1 = 2 * i + 3;
        // Ph1: tile 2i (buf0) c=0
        STG_B(1, 2, t1);
        VM7; BARR;
        RD_A(0); RD_B(0, 0); MFMA_PH(0);
        BARR;
        // Ph2: c=1
        STG_A(0, 0, s0); STG_A(0, 1, s0); STG_B(0, 0, s0);
        BARR; RD_B(0, 1); MFMA_PH(1); BARR;
        // Ph3: c=2
        STG_A(0, 2, s0); STG_A(0, 3, s0); STG_B(0, 1, s0);
        BARR; RD_B(0, 2); MFMA_PH(2); BARR;
        // Ph4: tile 2i+1 (buf1) c=0
        STG_B(0, 2, s0);
        VM7; BARR;
        RD_A(1); RD_B(1, 0); MFMA_PH(0);
        BARR;
        // Ph5: c=1
        STG_A(1, 0, s1); STG_A(1, 1, s1); STG_B(1, 0, s1);
        BARR; RD_B(1, 1); MFMA_PH(1); BARR;
        // Ph6: c=2
        STG_A(1, 2, s1); STG_A(1, 3, s1); STG_B(1, 1, s1);
        BARR; RD_B(1, 2); MFMA_PH(2); BARR;
    }

    // tail: tile 14 (buf0, staged i=6 Ph2-4) then tile 15 (buf1; B2 staged here)
    STG_B(1, 2, 15);
    VM7; BARR;                 // completes {i6 Ph2,Ph3,Ph4} = buf0 tile 14
    RD_A(0); RD_B(0, 0); MFMA_PH(0);
    RD_B(0, 1); MFMA_PH(1);
    RD_B(0, 2); MFMA_PH(2);
    VM0; BARR;                 // all of tile 15 landed (all waves)
    RD_A(1); RD_B(1, 0); MFMA_PH(0);
    RD_B(1, 1); MFMA_PH(1);
    RD_B(1, 2); MFMA_PH(2);

    // epilogue: bias add + layout-specific bf16 store
    // wave wn's fc-fragment covers cols n0 + fc*64 + wn*16 + lrow
#pragma unroll
    for (int fc = 0; fc < 3; ++fc) {
        int col = n0 + fc * 64 + wn * 16 + lrow;     // 0..3071
        int z   = col >> 10;                          // 0=Q 1=K 2=V
        int c1  = col & 1023;
        short* dst = (z == 0) ? Qb : (z == 1) ? Kb : Vb;
        float bv = bf2f((uint16_t)ball[col]);
#pragma unroll
        for (int fr = 0; fr < 8; ++fr) {
#pragma unroll
            for (int g = 0; g < 4; ++g) {
                int m = m0 + wm * 128 + fr * 16 + quad * 4 + g;
                float fv = acc[fr][fc][g] + bv;
                int bh = (m >> 10) * 16 + (c1 >> 6);
                if (z == 2)   // V^T: [b,h,d=64,w=1024]
                    dst[(size_t)bh * 65536 + (size_t)(c1 & 63) * 1024 + (m & 1023)] =
                        (short)f2bf(fv);
                else          // Q/K: [b,h,w=1024,d=64]
                    dst[(size_t)bh * 65536 + (size_t)(m & 1023) * 64 + (c1 & 63)] =
                        (short)f2bf(fv);
            }
        }
    }
}

// ---------- flash attention, double-buffered + swizzled + NO-MAX softmax ----------
#define PSTR 72   // Ps row stride (shorts): 16B-aligned, 4-way max on writes
__global__ __launch_bounds__(512) void attn_kernel(
    const short* __restrict__ Q, const short* __restrict__ K,
    const short* __restrict__ Vt, const short* __restrict__ ErT,
    short* __restrict__ AV)
{
    __shared__ short Ks [2][64 * 64];
    __shared__ short Qks[2][64 * 64];
    __shared__ short Vs [2][64 * 64];
    __shared__ short Ps [128 * PSTR];
    const int tid  = threadIdx.x;
    const int wid  = tid >> 6;
    const int lane = tid & 63;
    const int lrow = lane & 15;
    const int quad = lane >> 4;
    const int lk   = quad * 8;
    const int srow = lane >> 3;
    const int sscol = (((lane & 7) ^ (srow & 7)) << 3);
    const int rx = lrow & 7;
    const int h = blockIdx.x, b = blockIdx.y;
    const int bh = b * 16 + h;
    const int i0 = blockIdx.z * 128;
    const int wrow = wid * 16;
    const short* Qbh = Q  + (size_t)bh * 65536;
    const short* Kbh = K  + (size_t)bh * 65536;
    const short* Vbh = Vt + (size_t)bh * 65536;

    short8 qa[4];
    {
        int row = i0 + wrow + lrow;
#pragma unroll
        for (int kk = 0; kk < 2; ++kk) {
            qa[kk]     = *(const short8*)&Qbh[(size_t)row * 64 + kk * 32 + lk];
            qa[kk + 2] = *(const short8*)&ErT[(size_t)row * 64 + kk * 32 + lk];
        }
    }

    float lrun[4];
    floatx4 oacc[4];
#pragma unroll
    for (int g = 0; g < 4; ++g) lrun[g] = 0.f;
#pragma unroll
    for (int c = 0; c < 4; ++c) oacc[c] = (floatx4){0.f, 0.f, 0.f, 0.f};

    {
        gll16(Kbh + (size_t)(wid * 8 + srow) * 64 + sscol,    &Ks [0][wid * 512 + lane * 8]);
        gll16(Qbh + (size_t)(wid * 8 + srow) * 64 + sscol,    &Qks[0][wid * 512 + lane * 8]);
        gll16(Vbh + (size_t)(wid * 8 + srow) * 1024 + sscol,  &Vs [0][wid * 512 + lane * 8]);
    }

    const float sc2 = 1.44269504088896f / 32.0f;

    for (int jt = 0; jt < 16; ++jt) {
        const int cur = jt & 1;
        __syncthreads();

        if (jt < 15) {
            int j1 = (jt + 1) * 64;
            gll16(Kbh + (size_t)(j1 + wid * 8 + srow) * 64 + sscol,    &Ks [cur ^ 1][wid * 512 + lane * 8]);
            gll16(Qbh + (size_t)(j1 + wid * 8 + srow) * 64 + sscol,    &Qks[cur ^ 1][wid * 512 + lane * 8]);
            gll16(Vbh + (size_t)(wid * 8 + srow) * 1024 + j1 + sscol,  &Vs [cur ^ 1][wid * 512 + lane * 8]);
        }

        floatx4 s[4];
#pragma unroll
        for (int c = 0; c < 4; ++c) s[c] = (floatx4){0.f, 0.f, 0.f, 0.f};
#pragma unroll
        for (int kk = 0; kk < 4; ++kk) {
            short8 kb[4];
#pragma unroll
            for (int c = 0; c < 4; ++c) {
                int kl = (kk < 2) ? kk : kk - 2;
                const short* src = (kk < 2) ? Ks[cur] : Qks[cur];
                kb[c] = *(const short8*)&src[(c * 16 + lrow) * 64 +
                                             (((kl * 4 + quad) ^ rx) << 3)];
            }
#pragma unroll
            for (int c = 0; c < 4; ++c)
                s[c] = mfma16(qa[kk], kb[c], s[c]);
        }

#pragma unroll
        for (int c = 0; c < 4; ++c)
#pragma unroll
            for (int g = 0; g < 4; ++g)
                s[c][g] = exp2f(s[c][g] * sc2);
#pragma unroll
        for (int g = 0; g < 4; ++g) {
            float rs = (s[0][g] + s[1][g]) + (s[2][g] + s[3][g]);
#pragma unroll
            for (int d = 1; d < 16; d <<= 1) rs += __shfl_xor(rs, d, 64);
            lrun[g] += rs;
        }

#pragma unroll
        for (int c = 0; c < 4; ++c)
#pragma unroll
            for (int g = 0; g < 4; ++g)
                Ps[(wrow + quad * 4 + g) * PSTR + c * 16 + lrow] = (short)f2bf(s[c][g]);
        __asm__ __volatile__("" ::: "memory");

#pragma unroll
        for (int kk = 0; kk < 2; ++kk) {
            short8 pa, vb[4];
            pa = *(const short8*)&Ps[(wrow + lrow) * PSTR + kk * 32 + lk];
#pragma unroll
            for (int c = 0; c < 4; ++c)
                vb[c] = *(const short8*)&Vs[cur][(c * 16 + lrow) * 64 +
                                                 (((kk * 4 + quad) ^ rx) << 3)];
#pragma unroll
            for (int c = 0; c < 4; ++c)
                oacc[c] = mfma16(pa, vb[c], oacc[c]);
        }
    }

#pragma unroll
    for (int c = 0; c < 4; ++c)
#pragma unroll
        for (int g = 0; g < 4; ++g) {
            int row = i0 + wrow + quad * 4 + g;
            int colc = h * 64 + c * 16 + lrow;
            AV[((size_t)b * 1024 + row) * 1024 + colc] = (short)f2bf(oacc[c][g] / lrun[g]);
        }
}

// ---------- launcher ----------
extern "C" void kernel_launch(void* const* d_in, const int* in_sizes, int n_in,
                              void* d_out, int out_size, void* d_ws, size_t ws_size,
                              hipStream_t stream) {
    const float* x  = (const float*)d_in[0];
    const float* Wq = (const float*)d_in[1];
    const float* bq = (const float*)d_in[2];
    const float* Wk = (const float*)d_in[3];
    const float* bk = (const float*)d_in[4];
    const float* Wv = (const float*)d_in[5];
    const float* bv = (const float*)d_in[6];
    const float* Wo = (const float*)d_in[7];
    const float* bo = (const float*)d_in[8];
    const float* er = (const float*)d_in[9];
    float* out = (float*)d_out;

    const size_t M1 = 1u << 20;
    short* ws   = (short*)d_ws;
    short* xb   = (short*)d_out;      // bf16 x in d_out's first 8MB; dead before out_gemm
    short* Qb   = ws;                 // 4M  [b,h,w,d]
    short* Kb   = ws + 4 * M1;        // 4M  [b,h,w,d]
    short* Vb   = ws + 8 * M1;        // 4M  [b,h,d,w]
    short* AVb  = ws + 12 * M1;       // 4M  [b,w,c]
    short* Wb   = ws + 16 * M1;       // 4M  (Wq|Wk|Wv|Wo bf16, contiguous)
    short* ball = ws + 20 * M1;       // 4x1024 (bq,bk,bv,bo)
    short* ErT  = ws + 20 * M1 + 4096; // 65536 [w,d]

    static bool attr_done = false;
    if (!attr_done) {
        hipFuncSetAttribute((const void*)qkv_gemm192,
                            hipFuncAttributeMaxDynamicSharedMemorySize, 114688);
        attr_done = true;
    }

    hipLaunchKernelGGL(conv_all, dim3(8464), dim3(256), 0, stream,
                       x, Wq, Wk, Wv, Wo, bq, bk, bv, bo, er, xb, Wb, ball, ErT);
    hipLaunchKernelGGL(qkv_gemm192, dim3(256), dim3(512), 114688, stream,
                       xb, Wb, ball, Qb, Kb, Vb);
    hipLaunchKernelGGL(attn_kernel, dim3(16, 4, 8), dim3(512), 0, stream,
                       Qb, Kb, Vb, ErT, AVb);
    hipLaunchKernelGGL(out_gemm, dim3(32, 8), dim3(256), 0, stream,
                       AVb, Wb + 3 * M1, ball + 3072, out);
}

// Round 5
// 201.486 us; speedup vs baseline: 1.0799x; 1.0393x over previous
//
#include <hip/hip_runtime.h>
#include <stdint.h>

// ---------- types / helpers ----------
typedef __attribute__((ext_vector_type(8))) short   short8;   // 8 bf16 (4 VGPRs)
typedef __attribute__((ext_vector_type(8))) __bf16  bf16x8;
typedef __attribute__((ext_vector_type(4))) float   floatx4;

__device__ __forceinline__ float bf2f(uint16_t h) {
    union { uint32_t u; float f; } v; v.u = ((uint32_t)h) << 16; return v.f;
}
__device__ __forceinline__ uint16_t f2bf(float f) {
    union { float f; uint32_t u; } v; v.f = f;
    uint32_t u = v.u;
    u += 0x7FFFu + ((u >> 16) & 1u);   // RNE
    return (uint16_t)(u >> 16);
}
__device__ __forceinline__ floatx4 mfma16(short8 a, short8 b, floatx4 c) {
    return __builtin_amdgcn_mfma_f32_16x16x32_bf16(
        __builtin_bit_cast(bf16x8, a), __builtin_bit_cast(bf16x8, b), c, 0, 0, 0);
}
// async global->LDS, 16B per lane
__device__ __forceinline__ void gll16(const short* g, short* l) {
    __builtin_amdgcn_global_load_lds(
        (const __attribute__((address_space(1))) uint32_t*)g,
        (__attribute__((address_space(3))) uint32_t*)l, 16, 0, 0);
}
// XOR bank swizzle: physical 16B-group = logical group ^ (row & 7).
// Applied to the GLOBAL source column during staging and to the group index
// on LDS reads. Kills the 128B-row-stride 16-way conflict. [R12: 1.94e7->5e5]

// ---------- merged f32->bf16 conversion (x, 4 weights, 4 biases, er^T) ----------
__global__ void conv_all(
    const float* __restrict__ x,
    const float* __restrict__ Wq, const float* __restrict__ Wk,
    const float* __restrict__ Wv, const float* __restrict__ Wo,
    const float* __restrict__ bq, const float* __restrict__ bk,
    const float* __restrict__ bv, const float* __restrict__ bo,
    const float* __restrict__ er,
    short* __restrict__ xb, short* __restrict__ Wb,
    short* __restrict__ ball, short* __restrict__ ErT)
{
    int blk = blockIdx.x, tid = threadIdx.x;
    if (blk < 4096) {                            // x: 1M float4
        int i = blk * 256 + tid;
        float4 v = ((const float4*)x)[i];
        ((short4*)xb)[i] = make_short4((short)f2bf(v.x), (short)f2bf(v.y),
                                       (short)f2bf(v.z), (short)f2bf(v.w));
    } else if (blk < 8192) {                     // weights: 4 x 256K float4
        int rel = blk - 4096;
        int wsel = rel >> 10;
        int i = (rel & 1023) * 256 + tid;
        const float* W = (wsel == 0) ? Wq : (wsel == 1) ? Wk : (wsel == 2) ? Wv : Wo;
        float4 v = ((const float4*)W)[i];
        ((short4*)(Wb + ((size_t)wsel << 20)))[i] =
            make_short4((short)f2bf(v.x), (short)f2bf(v.y),
                        (short)f2bf(v.z), (short)f2bf(v.w));
    } else if (blk < 8448) {                     // er[64][1024] -> ErT[1024][64]
        int idx = (blk - 8192) * 256 + tid;
        int w = idx >> 6, d = idx & 63;
        ErT[idx] = (short)f2bf(er[d * 1024 + w]);
    } else {                                     // biases: 4 x 1024
        int idx = (blk - 8448) * 256 + tid;
        int sel = idx >> 10, j = idx & 1023;
        const float* s = (sel == 0) ? bq : (sel == 1) ? bk : (sel == 2) ? bv : bo;
        ball[idx] = (short)f2bf(s[j]);
    }
}

// ---------- legacy GEMM body (m97-style 128x128) — still used by out_gemm ----------
__device__ __forceinline__ void gemm_body(
    const short* __restrict__ A, const short* __restrict__ Wt,
    const short* __restrict__ bias, short* __restrict__ dst,
    float* __restrict__ dstf, int variant)
{
    __shared__ short As[128 * 64];
    __shared__ short Bs[128 * 64];
    const int tid  = threadIdx.x;
    const int wid  = tid >> 6;
    const int lane = tid & 63;
    const int m0 = blockIdx.x * 128;
    const int n0 = blockIdx.y * 128;
    const int wm = (wid >> 1) * 64;
    const int wn = (wid & 1) * 64;
    const int lrow = lane & 15;
    const int quad = lane >> 4;
    const int srow = lane >> 3;
    const int sscol = (((lane & 7) ^ (srow & 7)) << 3);
    const int rx = lrow & 7;

    floatx4 acc[4][4];
#pragma unroll
    for (int r = 0; r < 4; ++r)
#pragma unroll
        for (int c = 0; c < 4; ++c) acc[r][c] = (floatx4){0.f, 0.f, 0.f, 0.f};

    for (int k0 = 0; k0 < 1024; k0 += 64) {
#pragma unroll
        for (int i = 0; i < 4; ++i) {
            int q = wid * 4 + i;
            gll16(A + (size_t)(m0 + q * 8 + srow) * 1024 + k0 + sscol,
                  &As[q * 512 + lane * 8]);
        }
#pragma unroll
        for (int i = 0; i < 4; ++i) {
            int q = wid * 4 + i;
            gll16(Wt + (size_t)(n0 + q * 8 + srow) * 1024 + k0 + sscol,
                  &Bs[q * 512 + lane * 8]);
        }
        __syncthreads();
#pragma unroll
        for (int ks = 0; ks < 2; ++ks) {
            short8 af[4], bfr[4];
#pragma unroll
            for (int r = 0; r < 4; ++r)
                af[r] = *(const short8*)&As[(wm + r * 16 + lrow) * 64 +
                                            (((ks * 4 + quad) ^ rx) << 3)];
#pragma unroll
            for (int c = 0; c < 4; ++c)
                bfr[c] = *(const short8*)&Bs[(wn + c * 16 + lrow) * 64 +
                                             (((ks * 4 + quad) ^ rx) << 3)];
#pragma unroll
            for (int r = 0; r < 4; ++r)
#pragma unroll
                for (int c = 0; c < 4; ++c)
                    acc[r][c] = mfma16(af[r], bfr[c], acc[r][c]);
        }
        __syncthreads();
    }

#pragma unroll
    for (int c = 0; c < 4; ++c) {
        int col = n0 + wn + c * 16 + lrow;
        float bv = bf2f((uint16_t)bias[col]);
#pragma unroll
        for (int r = 0; r < 4; ++r) {
#pragma unroll
            for (int g = 0; g < 4; ++g) {
                int m = m0 + wm + r * 16 + quad * 4 + g;
                float fv = acc[r][c][g] + bv;
                if (variant == 3) {
                    dstf[(size_t)m * 1024 + col] = fv;
                } else if (variant == 2) {
                    int bh = (m >> 10) * 16 + (col >> 6);
                    dst[(size_t)bh * 65536 + (size_t)(col & 63) * 1024 + (m & 1023)] =
                        (short)f2bf(fv);
                } else {
                    int bh = (m >> 10) * 16 + (col >> 6);
                    dst[(size_t)bh * 65536 + (size_t)(m & 1023) * 64 + (col & 63)] =
                        (short)f2bf(fv);
                }
            }
        }
    }
}

__global__ __launch_bounds__(256) void out_gemm(
    const short* __restrict__ AV, const short* __restrict__ Wo,
    const short* __restrict__ bo, float* __restrict__ out)
{
    gemm_body(AV, Wo, bo, nullptr, out, 3);
}

// ---------- fused QKV GEMM: 256x192 tile, BK=64, grid=256 blocks (ALL CUs) ----------
// (unchanged from R4 — verified correct & faster; see comments there)
#define VM7  asm volatile("s_waitcnt vmcnt(7)" ::: "memory")
#define VM6  asm volatile("s_waitcnt vmcnt(6)" ::: "memory")
#define VM0  asm volatile("s_waitcnt vmcnt(0)" ::: "memory")
#define BARR asm volatile("s_barrier" ::: "memory")

// stage one 64x64 subtile (row-major src, ld=1024) into an 8KB LDS region
__device__ __forceinline__ void stage_unit(const short* src, short* region, int tid)
{
    const int row  = tid >> 3;                       // 0..63
    const int scol = (((tid & 7) ^ (row & 7)) << 3); // swizzled source col (shorts)
    gll16(src + (size_t)row * 1024 + scol, region + tid * 8);
}

#define SAU(buf, u) (As + (buf) * 16384 + (u) * 4096)
#define SBU(buf, u) (Bs + (buf) * 12288 + (u) * 4096)
#define STG_A(buf, u, kt) stage_unit(Asrc + (size_t)(u) * 65536 + (size_t)(kt) * 64, SAU(buf, u), tid)
#define STG_B(buf, u, kt) stage_unit(Bsrc + (size_t)(u) * 65536 + (size_t)(kt) * 64, SBU(buf, u), tid)

#define RD_A(buf) do { \
    _Pragma("unroll") for (int fr_ = 0; fr_ < 8; ++fr_) { \
        const short* p_ = SAU(buf, wm * 2 + (fr_ >> 2)) + ((fr_ & 3) * 16 + lrow) * 64; \
        _Pragma("unroll") for (int ks_ = 0; ks_ < 2; ++ks_) \
            a[fr_][ks_] = *(const short8*)&p_[((ks_ * 4 + quad) ^ rx) << 3]; \
    } } while (0)

// phase c reads ONLY unit c; wave wn owns rows wn*16..wn*16+15 of that unit
#define RD_B(buf, c) do { \
    const short* p_ = SBU(buf, c) + (wn * 16 + lrow) * 64; \
    _Pragma("unroll") for (int ks_ = 0; ks_ < 2; ++ks_) \
        bb[ks_] = *(const short8*)&p_[((ks_ * 4 + quad) ^ rx) << 3]; \
    } while (0)

#define MFMA_PH(c) do { \
    __builtin_amdgcn_s_setprio(1); \
    _Pragma("unroll") for (int ks_ = 0; ks_ < 2; ++ks_) \
        _Pragma("unroll") for (int fr_ = 0; fr_ < 8; ++fr_) \
            acc[fr_][c] = mfma16(a[fr_][ks_], bb[ks_], acc[fr_][c]); \
    __builtin_amdgcn_s_setprio(0); \
    } while (0)

__global__ __launch_bounds__(512, 2) void qkv_gemm192(
    const short* __restrict__ x, const short* __restrict__ Wb,
    const short* __restrict__ ball,
    short* __restrict__ Qb, short* __restrict__ Kb, short* __restrict__ Vb)
{
    extern __shared__ short lds[];
    short* As = lds;              // 2 buf x 4 units x 4096 shorts = 64 KiB
    short* Bs = lds + 32768;      // 2 buf x 3 units x 4096 shorts = 48 KiB
    const int tid  = threadIdx.x;
    const int wid  = tid >> 6;
    const int lane = tid & 63;
    const int wm   = wid >> 2;          // 0..1  (M warp)
    const int wn   = wid & 3;           // 0..3  (N warp)
    const int lrow = lane & 15;
    const int quad = lane >> 4;
    const int rx   = lrow & 7;
    const int bid  = blockIdx.x;
    const int swz  = (bid & 7) * 32 + (bid >> 3);   // bijective XCD chunking
    const int mi   = swz & 15, ni = swz >> 4;
    const int m0   = mi * 256, n0 = ni * 192;
    const short* Asrc = x  + (size_t)m0 * 1024;
    const short* Bsrc = Wb + (size_t)n0 * 1024;

    floatx4 acc[8][3];
#pragma unroll
    for (int r = 0; r < 8; ++r)
#pragma unroll
        for (int c = 0; c < 3; ++c) acc[r][c] = (floatx4){0.f, 0.f, 0.f, 0.f};

    short8 a[8][2], bb[2];

    // prologue: buf0 <- tile0 (7 units), buf1 <- tile1 (6 units; B2 lands in Ph1)
    STG_A(0, 0, 0); STG_A(0, 1, 0); STG_A(0, 2, 0); STG_A(0, 3, 0);
    STG_B(0, 0, 0); STG_B(0, 1, 0); STG_B(0, 2, 0);
    STG_A(1, 0, 1); STG_A(1, 1, 1); STG_A(1, 2, 1); STG_A(1, 3, 1);
    STG_B(1, 0, 1); STG_B(1, 1, 1);
    VM6; BARR;

#pragma unroll 1
    for (int i = 0; i < 7; ++i) {
        const int t1 = 2 * i + 1, s0 = 2 * i + 2, s1 = 2 * i + 3;
        // Ph1: tile 2i (buf0) c=0
        STG_B(1, 2, t1);
        VM7; BARR;
        RD_A(0); RD_B(0, 0); MFMA_PH(0);
        BARR;
        // Ph2: c=1
        STG_A(0, 0, s0); STG_A(0, 1, s0); STG_B(0, 0, s0);
        BARR; RD_B(0, 1); MFMA_PH(1); BARR;
        // Ph3: c=2
        STG_A(0, 2, s0); STG_A(0, 3, s0); STG_B(0, 1, s0);
        BARR; RD_B(0, 2); MFMA_PH(2); BARR;
        // Ph4: tile 2i+1 (buf1) c=0
        STG_B(0, 2, s0);
        VM7; BARR;
        RD_A(1); RD_B(1, 0); MFMA_PH(0);
        BARR;
        // Ph5: c=1
        STG_A(1, 0, s1); STG_A(1, 1, s1); STG_B(1, 0, s1);
        BARR; RD_B(1, 1); MFMA_PH(1); BARR;
        // Ph6: c=2
        STG_A(1, 2, s1); STG_A(1, 3, s1); STG_B(1, 1, s1);
        BARR; RD_B(1, 2); MFMA_PH(2); BARR;
    }

    // tail: tile 14 (buf0, staged i=6 Ph2-4) then tile 15 (buf1; B2 staged here)
    STG_B(1, 2, 15);
    VM7; BARR;                 // completes {i6 Ph2,Ph3,Ph4} = buf0 tile 14
    RD_A(0); RD_B(0, 0); MFMA_PH(0);
    RD_B(0, 1); MFMA_PH(1);
    RD_B(0, 2); MFMA_PH(2);
    VM0; BARR;                 // all of tile 15 landed (all waves)
    RD_A(1); RD_B(1, 0); MFMA_PH(0);
    RD_B(1, 1); MFMA_PH(1);
    RD_B(1, 2); MFMA_PH(2);

    // epilogue: bias add + layout-specific bf16 store
    // wave wn's fc-fragment covers cols n0 + fc*64 + wn*16 + lrow
#pragma unroll
    for (int fc = 0; fc < 3; ++fc) {
        int col = n0 + fc * 64 + wn * 16 + lrow;     // 0..3071
        int z   = col >> 10;                          // 0=Q 1=K 2=V
        int c1  = col & 1023;
        short* dst = (z == 0) ? Qb : (z == 1) ? Kb : Vb;
        float bv = bf2f((uint16_t)ball[col]);
#pragma unroll
        for (int fr = 0; fr < 8; ++fr) {
#pragma unroll
            for (int g = 0; g < 4; ++g) {
                int m = m0 + wm * 128 + fr * 16 + quad * 4 + g;
                float fv = acc[fr][fc][g] + bv;
                int bh = (m >> 10) * 16 + (c1 >> 6);
                if (z == 2)   // V^T: [b,h,d=64,w=1024]
                    dst[(size_t)bh * 65536 + (size_t)(c1 & 63) * 1024 + (m & 1023)] =
                        (short)f2bf(fv);
                else          // Q/K: [b,h,w=1024,d=64]
                    dst[(size_t)bh * 65536 + (size_t)(m & 1023) * 64 + (c1 & 63)] =
                        (short)f2bf(fv);
            }
        }
    }
}

// ---------- flash attention v2: column-split waves + deferred row-sum ----------
// R5: attn was ~60% LDS-BW-bound (26 ds_read_b128/wave/jt; all 8 waves read the
// SAME K/Q B-frags = 8x duplication). New wave tiling: 8 waves = 4 row-groups
// (32 q-rows) x 2 col-groups (32 j's).  Per wave/jt: kb 16->8KB, vb 8->4KB.
// P stays WAVE-PRIVATE (32x32 block) so no new barriers in the jt loop.
// oacc/lrun are j-partial; combined ONCE at the end via f32 LDS scratch
// overlapping the K/Q staging region (dead by then). Row-sum butterfly moved
// out of the jt loop (per-lane accumulate; one 16-lane reduce at the end).
#define PSTR 72   // Ps row stride (shorts): 16B-aligned
__global__ __launch_bounds__(512, 4) void attn_kernel(
    const short* __restrict__ Q, const short* __restrict__ K,
    const short* __restrict__ Vt, const short* __restrict__ ErT,
    short* __restrict__ AV)
{
    __shared__ short smem[33792];            // 66 KiB, flat
    short* Ks  = smem;                       // [2][4096]
    short* Qks = smem + 8192;                // [2][4096]
    short* Vs  = smem + 16384;               // [2][4096]
    short* Ps  = smem + 24576;               // [128*PSTR]
    float* oaccS = (float*)smem;             // [128][65] f32 end-combine scratch
    float* lrunS = ((float*)smem) + 128 * 65; // 128 f32
    // scratch spans shorts 0..16895: Ks(all) + Qks(all) + head of Vs[0].
    // Vs[0] is last read at jt=14, Ks/Qks[1] at jt=15 — all before the
    // post-loop __syncthreads that precedes any scratch write.

    const int tid  = threadIdx.x;
    const int wid  = tid >> 6;
    const int lane = tid & 63;
    const int rg   = wid >> 1;          // 0..3: row-group (32 q-rows)
    const int cg   = wid & 1;           // 0..1: col-group (32 j's)
    const int lrow = lane & 15;
    const int quad = lane >> 4;
    const int lk   = quad * 8;
    const int srow = lane >> 3;
    const int sscol = (((lane & 7) ^ (srow & 7)) << 3);
    const int rx = lrow & 7;
    const int h = blockIdx.x, b = blockIdx.y;
    const int bh = b * 16 + h;
    const int i0 = blockIdx.z * 128;
    const short* Qbh = Q  + (size_t)bh * 65536;
    const short* Kbh = K  + (size_t)bh * 65536;
    const short* Vbh = Vt + (size_t)bh * 65536;

    // Qaug A-frags: 32 rows (2 m-tiles) x full K=128 ([Q | ErT])
    short8 qa[2][4];
#pragma unroll
    for (int m = 0; m < 2; ++m) {
        int row = i0 + rg * 32 + m * 16 + lrow;
#pragma unroll
        for (int kk = 0; kk < 2; ++kk) {
            qa[m][kk]     = *(const short8*)&Qbh[(size_t)row * 64 + kk * 32 + lk];
            qa[m][kk + 2] = *(const short8*)&ErT[(size_t)row * 64 + kk * 32 + lk];
        }
    }

    float lrun[2][4];
    floatx4 oacc[2][4];
#pragma unroll
    for (int m = 0; m < 2; ++m) {
#pragma unroll
        for (int g = 0; g < 4; ++g) lrun[m][g] = 0.f;
#pragma unroll
        for (int c = 0; c < 4; ++c) oacc[m][c] = (floatx4){0.f, 0.f, 0.f, 0.f};
    }

    // prologue: stage jt=0 into buffer 0 (wave wid stages chunk wid of each)
    gll16(Kbh + (size_t)(wid * 8 + srow) * 64 + sscol,    Ks  + wid * 512 + lane * 8);
    gll16(Qbh + (size_t)(wid * 8 + srow) * 64 + sscol,    Qks + wid * 512 + lane * 8);
    gll16(Vbh + (size_t)(wid * 8 + srow) * 1024 + sscol,  Vs  + wid * 512 + lane * 8);

    const float sc2 = 1.44269504088896f / 32.0f;   // log2(e)/sqrt(c)

    for (int jt = 0; jt < 16; ++jt) {
        const int cur = jt & 1;
        __syncthreads();   // buf[cur] staged + all waves done reading it last round

        if (jt < 15) {     // prefetch jt+1 into buf[cur^1]
            int j1 = (jt + 1) * 64;
            gll16(Kbh + (size_t)(j1 + wid * 8 + srow) * 64 + sscol,    Ks  + (cur ^ 1) * 4096 + wid * 512 + lane * 8);
            gll16(Qbh + (size_t)(j1 + wid * 8 + srow) * 64 + sscol,    Qks + (cur ^ 1) * 4096 + wid * 512 + lane * 8);
            gll16(Vbh + (size_t)(wid * 8 + srow) * 1024 + j1 + sscol,  Vs  + (cur ^ 1) * 4096 + wid * 512 + lane * 8);
        }

        // S-MFMA: rows rg*32..+31 x cols (j) cg*32..+31
        floatx4 s[2][2];
#pragma unroll
        for (int m = 0; m < 2; ++m)
#pragma unroll
            for (int c = 0; c < 2; ++c) s[m][c] = (floatx4){0.f, 0.f, 0.f, 0.f};
#pragma unroll
        for (int kk = 0; kk < 4; ++kk) {
            short8 kb[2];
            const short* src = ((kk < 2) ? Ks : Qks) + cur * 4096;
            const int kl = kk & 1;
#pragma unroll
            for (int c = 0; c < 2; ++c)
                kb[c] = *(const short8*)&src[(cg * 32 + c * 16 + lrow) * 64 +
                                             (((kl * 4 + quad) ^ rx) << 3)];
#pragma unroll
            for (int m = 0; m < 2; ++m)
#pragma unroll
                for (int c = 0; c < 2; ++c)
                    s[m][c] = mfma16(qa[m][kk], kb[c], s[m][c]);
        }

        // no-max softmax: p = exp2(s*sc2); per-lane partial row sums (deferred)
#pragma unroll
        for (int m = 0; m < 2; ++m)
#pragma unroll
            for (int c = 0; c < 2; ++c)
#pragma unroll
                for (int g = 0; g < 4; ++g)
                    s[m][c][g] = exp2f(s[m][c][g] * sc2);
#pragma unroll
        for (int m = 0; m < 2; ++m)
#pragma unroll
            for (int g = 0; g < 4; ++g)
                lrun[m][g] += s[m][0][g] + s[m][1][g];

        // write P to wave-private 32x32 block of Ps
#pragma unroll
        for (int m = 0; m < 2; ++m)
#pragma unroll
            for (int c = 0; c < 2; ++c)
#pragma unroll
                for (int g = 0; g < 4; ++g)
                    Ps[(rg * 32 + m * 16 + quad * 4 + g) * PSTR + cg * 32 + c * 16 + lrow] =
                        (short)f2bf(s[m][c][g]);
        __asm__ __volatile__("" ::: "memory");

        // PV-MFMA: k = wave's 32 j's (single K=32 step)
        {
            short8 pa[2], vb[4];
#pragma unroll
            for (int m = 0; m < 2; ++m)
                pa[m] = *(const short8*)&Ps[(rg * 32 + m * 16 + lrow) * PSTR + cg * 32 + lk];
#pragma unroll
            for (int c = 0; c < 4; ++c)
                vb[c] = *(const short8*)&Vs[cur * 4096 + (c * 16 + lrow) * 64 +
                                            (((cg * 4 + quad) ^ rx) << 3)];
#pragma unroll
            for (int m = 0; m < 2; ++m)
#pragma unroll
                for (int c = 0; c < 4; ++c)
                    oacc[m][c] = mfma16(pa[m], vb[c], oacc[m][c]);
        }
    }

    // ---- end-combine across the 2 col-groups ----
    // finish the 16-lane row-sum reduce (all lanes get their lrow-group sum)
#pragma unroll
    for (int m = 0; m < 2; ++m)
#pragma unroll
        for (int g = 0; g < 4; ++g) {
            float r = lrun[m][g];
#pragma unroll
            for (int d = 1; d < 16; d <<= 1) r += __shfl_xor(r, d, 64);
            lrun[m][g] = r;
        }

    __syncthreads();   // all LDS reads of the jt loop complete
    if (cg == 0) {
#pragma unroll
        for (int m = 0; m < 2; ++m) {
#pragma unroll
            for (int c = 0; c < 4; ++c)
#pragma unroll
                for (int g = 0; g < 4; ++g)
                    oaccS[(rg * 32 + m * 16 + quad * 4 + g) * 65 + c * 16 + lrow] =
                        oacc[m][c][g];
            if (lrow == 0)
#pragma unroll
                for (int g = 0; g < 4; ++g)
                    lrunS[rg * 32 + m * 16 + quad * 4 + g] = lrun[m][g];
        }
    }
    __syncthreads();
    if (cg == 1) {
#pragma unroll
        for (int m = 0; m < 2; ++m)
#pragma unroll
            for (int g = 0; g < 4; ++g) {
                int row = rg * 32 + m * 16 + quad * 4 + g;
                float lt = lrun[m][g] + lrunS[row];
#pragma unroll
                for (int c = 0; c < 4; ++c) {
                    float tot = oacc[m][c][g] + oaccS[row * 65 + c * 16 + lrow];
                    AV[((size_t)b * 1024 + i0 + row) * 1024 + h * 64 + c * 16 + lrow] =
                        (short)f2bf(tot / lt);
                }
            }
    }
}

// ---------- launcher ----------
extern "C" void kernel_launch(void* const* d_in, const int* in_sizes, int n_in,
                              void* d_out, int out_size, void* d_ws, size_t ws_size,
                              hipStream_t stream) {
    const float* x  = (const float*)d_in[0];
    const float* Wq = (const float*)d_in[1];
    const float* bq = (const float*)d_in[2];
    const float* Wk = (const float*)d_in[3];
    const float* bk = (const float*)d_in[4];
    const float* Wv = (const float*)d_in[5];
    const float* bv = (const float*)d_in[6];
    const float* Wo = (const float*)d_in[7];
    const float* bo = (const float*)d_in[8];
    const float* er = (const float*)d_in[9];
    float* out = (float*)d_out;

    const size_t M1 = 1u << 20;
    short* ws   = (short*)d_ws;
    short* xb   = (short*)d_out;      // bf16 x in d_out's first 8MB; dead before out_gemm
    short* Qb   = ws;                 // 4M  [b,h,w,d]
    short* Kb   = ws + 4 * M1;        // 4M  [b,h,w,d]
    short* Vb   = ws + 8 * M1;        // 4M  [b,h,d,w]
    short* AVb  = ws + 12 * M1;       // 4M  [b,w,c]
    short* Wb   = ws + 16 * M1;       // 4M  (Wq|Wk|Wv|Wo bf16, contiguous)
    short* ball = ws + 20 * M1;       // 4x1024 (bq,bk,bv,bo)
    short* ErT  = ws + 20 * M1 + 4096; // 65536 [w,d]

    static bool attr_done = false;
    if (!attr_done) {
        hipFuncSetAttribute((const void*)qkv_gemm192,
                            hipFuncAttributeMaxDynamicSharedMemorySize, 114688);
        attr_done = true;
    }

    hipLaunchKernelGGL(conv_all, dim3(8464), dim3(256), 0, stream,
                       x, Wq, Wk, Wv, Wo, bq, bk, bv, bo, er, xb, Wb, ball, ErT);
    hipLaunchKernelGGL(qkv_gemm192, dim3(256), dim3(512), 114688, stream,
                       xb, Wb, ball, Qb, Kb, Vb);
    hipLaunchKernelGGL(attn_kernel, dim3(16, 4, 8), dim3(512), 0, stream,
                       Qb, Kb, Vb, ErT, AVb);
    hipLaunchKernelGGL(out_gemm, dim3(32, 8), dim3(256), 0, stream,
                       AVb, Wb + 3 * M1, ball + 3072, out);
}